// Round 1
// baseline (746.231 us; speedup 1.0000x reference)
//
#include <hip/hip_runtime.h>
#include <hip/hip_bf16.h>
#include <stdint.h>

typedef unsigned short u16;
typedef __bf16 bf16x8 __attribute__((ext_vector_type(8)));
typedef __attribute__((ext_vector_type(4))) float f32x4;
typedef __attribute__((ext_vector_type(4))) unsigned short u16x4;

#define T_ 2048

__device__ __forceinline__ u16 f2bf(float f) {
  __hip_bfloat16 h = __float2bfloat16(f);
  return __builtin_bit_cast(u16, h);
}
__device__ __forceinline__ float bf2f(u16 u) {
  __hip_bfloat16 h = __builtin_bit_cast(__hip_bfloat16, u);
  return __bfloat162float(h);
}
// async global->LDS, 16B per lane. lds ptr must be wave-uniform base; lane i
// lands at base + i*16.
__device__ __forceinline__ void g2l16(const void* g, void* l) {
  __builtin_amdgcn_global_load_lds(
      (const __attribute__((address_space(1))) void*)g,
      (__attribute__((address_space(3))) void*)l, 16, 0, 0);
}

// ---------------- casts ----------------
__global__ __launch_bounds__(256) void cast_f32_bf16(const float* __restrict__ in,
                                                     u16* __restrict__ outp, int n) {
  int i = (blockIdx.x * 256 + threadIdx.x) * 4;
  if (i < n) {
    f32x4 v = *(const f32x4*)(in + i);
    u16x4 o;
    o.x = f2bf(v.x); o.y = f2bf(v.y); o.z = f2bf(v.z); o.w = f2bf(v.w);
    *(u16x4*)(outp + i) = o;
  }
}

// in fp32 [R][C] -> out bf16 [Cpad][R]; cols >= C write 0 (zero padding rows).
__global__ __launch_bounds__(256) void castT(const float* __restrict__ in,
                                             u16* __restrict__ outp, int R, int C) {
  __shared__ float tile[32][33];
  int tx = threadIdx.x & 31, ty = threadIdx.x >> 5;  // ty 0..7
  int r0 = blockIdx.y * 32, c0 = blockIdx.x * 32;
#pragma unroll
  for (int p = 0; p < 4; p++) {
    int rr = r0 + ty + p * 8;
    int cc = c0 + tx;
    tile[ty + p * 8][tx] = (cc < C) ? in[(size_t)rr * C + cc] : 0.f;
  }
  __syncthreads();
#pragma unroll
  for (int p = 0; p < 4; p++) {
    outp[(size_t)(c0 + ty + p * 8) * R + r0 + tx] = f2bf(tile[tx][ty + p * 8]);
  }
}

// ---------------- rmsnorm over rows ----------------
// in/out bf16, weight fp32. D multiple of 256, D<=1536. May be in-place.
__global__ __launch_bounds__(256) void rmsnorm_rows(const u16* __restrict__ in,
                                                    u16* __restrict__ outp,
                                                    const float* __restrict__ w,
                                                    int D, int sin, int sout) {
  int r = blockIdx.x, tid = threadIdx.x;
  int wave = tid >> 6, lane = tid & 63;
  __shared__ float sred[4];
  float vals[6];
  int E = D >> 8;
  float ss = 0.f;
  for (int e = 0; e < E; e++) {
    float v = bf2f(in[(size_t)r * sin + e * 256 + tid]);
    vals[e] = v;
    ss += v * v;
  }
#pragma unroll
  for (int d = 1; d < 64; d <<= 1) ss += __shfl_xor(ss, d, 64);
  if (lane == 0) sred[wave] = ss;
  __syncthreads();
  ss = sred[0] + sred[1] + sred[2] + sred[3];
  float rr = rsqrtf(ss / (float)D + 1e-6f);
  for (int e = 0; e < E; e++)
    outp[(size_t)r * sout + e * 256 + tid] = f2bf(vals[e] * rr * w[e * 256 + tid]);
}

// ---------------- GEMM: C[M,N] = A[M,K] * Bt[N,K]^T  (bf16 in, fp32 acc) ----
__global__ __launch_bounds__(256) void gemm_bt(const u16* __restrict__ A,
                                               const u16* __restrict__ Bt,
                                               void* __restrict__ Cv,
                                               int M, int N, int K, int cf32) {
  __shared__ u16 As[128 * 32];
  __shared__ u16 Bs[128 * 32];
  const int tid = threadIdx.x;
  const int wave = tid >> 6, lane = tid & 63;
  const int m0 = blockIdx.y * 128, n0 = blockIdx.x * 128;
  const int wm = (wave >> 1) * 64, wn = (wave & 1) * 64;
  const int fr = lane & 15, fq = lane >> 4;
  f32x4 acc[4][4] = {};
  const int L = tid * 16;          // byte offset of this thread's 16B chunk
  const int r0 = L >> 6;           // tile row (64B per row = 32 bf16)
  const int ce = (L & 63) >> 1;    // col element offset
  const u16* ap = A + (size_t)(m0 + r0) * K + ce;
  const u16* bp = Bt + (size_t)(n0 + r0) * K + ce;
  u16* asd = As + wave * 512;      // wave-uniform LDS dest (1024B per wave)
  u16* bsd = Bs + wave * 512;
  for (int k0 = 0; k0 < K; k0 += 32) {
    g2l16(ap + k0, asd);
    g2l16(ap + (size_t)64 * K + k0, asd + 2048);
    g2l16(bp + k0, bsd);
    g2l16(bp + (size_t)64 * K + k0, bsd + 2048);
    __syncthreads();
    bf16x8 af[4], bf[4];
#pragma unroll
    for (int i = 0; i < 4; i++) {
      af[i] = *(const bf16x8*)(As + (wm + 16 * i + fr) * 32 + fq * 8);
      bf[i] = *(const bf16x8*)(Bs + (wn + 16 * i + fr) * 32 + fq * 8);
    }
#pragma unroll
    for (int i = 0; i < 4; i++)
#pragma unroll
      for (int j = 0; j < 4; j++)
        acc[i][j] = __builtin_amdgcn_mfma_f32_16x16x32_bf16(af[i], bf[j], acc[i][j], 0, 0, 0);
    __syncthreads();
  }
  // C/D layout: col = lane&15, row = (lane>>4)*4 + reg
  if (cf32) {
    float* C = (float*)Cv;
#pragma unroll
    for (int i = 0; i < 4; i++)
#pragma unroll
      for (int j = 0; j < 4; j++)
#pragma unroll
        for (int r = 0; r < 4; r++)
          C[(size_t)(m0 + wm + 16 * i + fq * 4 + r) * N + n0 + wn + 16 * j + fr] = acc[i][j][r];
  } else {
    u16* C = (u16*)Cv;
#pragma unroll
    for (int i = 0; i < 4; i++)
#pragma unroll
      for (int j = 0; j < 4; j++)
#pragma unroll
        for (int r = 0; r < 4; r++)
          C[(size_t)(m0 + wm + 16 * i + fq * 4 + r) * N + n0 + wn + 16 * j + fr] = f2bf(acc[i][j][r]);
  }
}

// ---------------- q pack: head rmsnorm + rope -> qp[bh][t][192] ------------
__global__ __launch_bounds__(256) void qpack(const u16* __restrict__ qn,
                                             const u16* __restrict__ qr,
                                             const float* __restrict__ qhw,
                                             const float* __restrict__ fcos,
                                             const float* __restrict__ fsin,
                                             u16* __restrict__ qp) {
  int gw = blockIdx.x * 4 + (threadIdx.x >> 6);
  int lane = threadIdx.x & 63;
  int r = gw >> 4, h = gw & 15;
  int b = r >> 11, t = r & 2047;
  float v0 = bf2f(qn[(size_t)r * 2048 + h * 128 + lane]);
  float v1 = bf2f(qn[(size_t)r * 2048 + h * 128 + 64 + lane]);
  float ss = v0 * v0 + v1 * v1;
#pragma unroll
  for (int d = 1; d < 64; d <<= 1) ss += __shfl_xor(ss, d, 64);
  float rr = rsqrtf(ss * (1.f / 128.f) + 1e-6f);
  size_t ob = ((size_t)(b * 16 + h) * 2048 + t) * 192;
  qp[ob + lane] = f2bf(v0 * rr * qhw[lane]);
  qp[ob + 64 + lane] = f2bf(v1 * rr * qhw[64 + lane]);
  if (lane < 32) {
    float a = bf2f(qr[(size_t)r * 1024 + h * 64 + 2 * lane]);
    float bb = bf2f(qr[(size_t)r * 1024 + h * 64 + 2 * lane + 1]);
    float c = fcos[t * 32 + lane], s = fsin[t * 32 + lane];
    qp[ob + 128 + 2 * lane] = f2bf(a * c - bb * s);
    qp[ob + 129 + 2 * lane] = f2bf(a * s + bb * c);
  }
}

// ---------------- kv pack: k head-norm + rope bcast; V tile-transpose ------
__global__ __launch_bounds__(256) void kvpack(const u16* __restrict__ kvu,
                                              const u16* __restrict__ kvr,
                                              const float* __restrict__ khw,
                                              const float* __restrict__ fcos,
                                              const float* __restrict__ fsin,
                                              u16* __restrict__ kp,
                                              u16* __restrict__ vp) {
  int h = blockIdx.x & 15, tile = blockIdx.x >> 4;
  int r0 = tile * 64;
  int b = r0 >> 11;
  int tl = tile & 31;
  int tid = threadIdx.x, wave = tid >> 6, lane = tid & 63;
  __shared__ u16 vsl[128 * 66];
  int bh = b * 16 + h;
  for (int ii = 0; ii < 16; ii++) {
    int i = wave * 16 + ii;
    int r = r0 + i;
    int t = r & 2047;
    size_t kbase = (size_t)r * 4096 + h * 256;
    float v0 = bf2f(kvu[kbase + lane]);
    float v1 = bf2f(kvu[kbase + 64 + lane]);
    float ss = v0 * v0 + v1 * v1;
#pragma unroll
    for (int d = 1; d < 64; d <<= 1) ss += __shfl_xor(ss, d, 64);
    float rr = rsqrtf(ss * (1.f / 128.f) + 1e-6f);
    size_t ob = ((size_t)bh * 2048 + t) * 192;
    kp[ob + lane] = f2bf(v0 * rr * khw[lane]);
    kp[ob + 64 + lane] = f2bf(v1 * rr * khw[64 + lane]);
    vsl[lane * 66 + i] = kvu[kbase + 128 + lane];
    vsl[(lane + 64) * 66 + i] = kvu[kbase + 192 + lane];
    if (lane < 32) {
      float a = bf2f(kvr[(size_t)r * 640 + 512 + 2 * lane]);
      float bb = bf2f(kvr[(size_t)r * 640 + 512 + 2 * lane + 1]);
      float c = fcos[t * 32 + lane], s = fsin[t * 32 + lane];
      kp[ob + 128 + 2 * lane] = f2bf(a * c - bb * s);
      kp[ob + 129 + 2 * lane] = f2bf(a * s + bb * c);
    }
  }
  __syncthreads();
  u16* vb = vp + ((size_t)bh * 32 + tl) * 8192;  // [128][64] tile
  for (int u = 0; u < 32; u++) {
    int e = u * 256 + tid;
    vb[e] = vsl[(e >> 6) * 66 + (e & 63)];
  }
}

// ---------------- flash attention (causal) ---------------------------------
// Q,K: [BH][T][192]; Vt: [BH][T/64][128][64] (v-dim major); O: [B*T][2048]
__global__ __launch_bounds__(256) void attn_kernel(const u16* __restrict__ Q,
                                                   const u16* __restrict__ Kp,
                                                   const u16* __restrict__ Vt,
                                                   u16* __restrict__ O) {
  __shared__ u16 Ks[64 * 192];
  __shared__ u16 Vs[128 * 64];
  __shared__ u16 Ps[4][16 * 64];
  const int tid = threadIdx.x;
  const int wave = tid >> 6, lane = tid & 63;
  const int bh = blockIdx.y;
  const int qt = (int)gridDim.x - 1 - (int)blockIdx.x;  // heavy blocks first
  const int fr = lane & 15, fq = lane >> 4;
  const int myq = qt * 64 + wave * 16 + fr;
  const float scale = 0.07216878364870323f;  // 1/sqrt(192)

  bf16x8 qf[6];
  {
    const u16* qb = Q + ((size_t)bh * T_ + myq) * 192 + fq * 8;
#pragma unroll
    for (int c = 0; c < 6; c++) qf[c] = *(const bf16x8*)(qb + c * 32);
  }
  f32x4 o[8] = {};
  float m_i[4], l_i[4];
#pragma unroll
  for (int r = 0; r < 4; r++) { m_i[r] = -3.0e38f; l_i[r] = 0.f; }

  const int Lk = tid * 16;  // byte offset for staging
  for (int j = 0; j <= qt; j++) {
    const char* kg = (const char*)(Kp + ((size_t)bh * T_ + j * 64) * 192);
    const char* vg = (const char*)(Vt + ((size_t)bh * 32 + j) * 8192);
#pragma unroll
    for (int is = 0; is < 6; is++)
      g2l16(kg + is * 4096 + Lk, (char*)Ks + is * 4096 + wave * 1024);
#pragma unroll
    for (int is = 0; is < 4; is++)
      g2l16(vg + is * 4096 + Lk, (char*)Vs + is * 4096 + wave * 1024);
    __syncthreads();

    // S = Q K^T for this wave's 16 q-rows x 64 k-cols
    f32x4 s[4] = {};
#pragma unroll
    for (int ni = 0; ni < 4; ni++) {
      const u16* kb = Ks + (16 * ni + fr) * 192 + fq * 8;
#pragma unroll
      for (int c = 0; c < 6; c++) {
        bf16x8 kf = *(const bf16x8*)(kb + c * 32);
        s[ni] = __builtin_amdgcn_mfma_f32_16x16x32_bf16(qf[c], kf, s[ni], 0, 0, 0);
      }
    }
    const int qg0 = qt * 64 + wave * 16 + fq * 4;
#pragma unroll
    for (int r = 0; r < 4; r++) {
#pragma unroll
      for (int ni = 0; ni < 4; ni++) s[ni][r] *= scale;
      if (j == qt) {
#pragma unroll
        for (int ni = 0; ni < 4; ni++)
          if (j * 64 + ni * 16 + fr > qg0 + r) s[ni][r] = -3.0e38f;
      }
      float mx = fmaxf(fmaxf(s[0][r], s[1][r]), fmaxf(s[2][r], s[3][r]));
#pragma unroll
      for (int d = 1; d < 16; d <<= 1) mx = fmaxf(mx, __shfl_xor(mx, d, 64));
      float mn = fmaxf(m_i[r], mx);
      float al = exp2f((m_i[r] - mn) * 1.44269504f);
      float rs = 0.f;
#pragma unroll
      for (int ni = 0; ni < 4; ni++) {
        float p = exp2f((s[ni][r] - mn) * 1.44269504f);
        s[ni][r] = p;
        rs += p;
      }
#pragma unroll
      for (int d = 1; d < 16; d <<= 1) rs += __shfl_xor(rs, d, 64);
      m_i[r] = mn;
      l_i[r] = l_i[r] * al + rs;
#pragma unroll
      for (int ti = 0; ti < 8; ti++) o[ti][r] *= al;
    }
    // P: C-layout -> LDS -> A-layout
    u16* pw = Ps[wave];
#pragma unroll
    for (int ni = 0; ni < 4; ni++)
#pragma unroll
      for (int r = 0; r < 4; r++)
        pw[(fq * 4 + r) * 64 + ni * 16 + fr] = f2bf(s[ni][r]);
    __syncthreads();
    // O += P V
#pragma unroll
    for (int c = 0; c < 2; c++) {
      bf16x8 pf = *(const bf16x8*)(pw + fr * 64 + c * 32 + fq * 8);
#pragma unroll
      for (int ti = 0; ti < 8; ti++) {
        bf16x8 vf = *(const bf16x8*)(Vs + (16 * ti + fr) * 64 + c * 32 + fq * 8);
        o[ti] = __builtin_amdgcn_mfma_f32_16x16x32_bf16(pf, vf, o[ti], 0, 0, 0);
      }
    }
    __syncthreads();
  }
  const int b = bh >> 4, h = bh & 15;
#pragma unroll
  for (int r = 0; r < 4; r++) {
    float inv = 1.f / l_i[r];
    int q = qt * 64 + wave * 16 + fq * 4 + r;
    u16* orow = O + ((size_t)(b * T_ + q)) * 2048 + h * 128 + fr;
#pragma unroll
    for (int ti = 0; ti < 8; ti++) orow[ti * 16] = f2bf(o[ti][r] * inv);
  }
}

extern "C" void kernel_launch(void* const* d_in, const int* in_sizes, int n_in,
                              void* d_out, int out_size, void* d_ws, size_t ws_size,
                              hipStream_t stream) {
  const float* x    = (const float*)d_in[0];
  const float* fcos = (const float*)d_in[1];
  const float* fsin = (const float*)d_in[2];
  const float* wqd  = (const float*)d_in[3];
  const float* qnw  = (const float*)d_in[4];
  const float* wqun = (const float*)d_in[5];
  const float* wqur = (const float*)d_in[6];
  const float* wkvd = (const float*)d_in[7];
  const float* kvnw = (const float*)d_in[8];
  const float* wkvu = (const float*)d_in[9];
  const float* qhnw = (const float*)d_in[10];
  const float* khnw = (const float*)d_in[11];
  const float* wwo  = (const float*)d_in[12];
  float* out = (float*)d_out;
  char* ws = (char*)d_ws;

  size_t off = 0;
  auto alloc = [&](size_t elems) -> u16* {
    u16* p = (u16*)(ws + off);
    off += ((elems * 2 + 255) & ~(size_t)255);
    return p;
  };
  u16* x16  = alloc(4096ull * 2048);
  u16* bqd  = alloc(1536ull * 2048);
  u16* bqun = alloc(2048ull * 1536);
  u16* bqur = alloc(1024ull * 1536);
  u16* bkvd = alloc(640ull * 2048);
  u16* bkvu = alloc(4096ull * 512);
  u16* bwo  = alloc(2048ull * 2048);
  u16* cq   = alloc(4096ull * 1536);
  u16* qn   = alloc(4096ull * 2048);
  u16* qr   = alloc(4096ull * 1024);
  u16* kvr  = alloc(4096ull * 640);
  u16* ckv  = alloc(4096ull * 512);
  u16* kvu  = alloc(4096ull * 4096);
  u16* qp   = alloc(32ull * 2048 * 192);
  u16* kp   = alloc(32ull * 2048 * 192);
  u16* vp   = alloc(32ull * 2048 * 128);
  u16* ao   = alloc(4096ull * 2048);
  if (ws_size < off) return;  // workspace too small -> loud failure

  cast_f32_bf16<<<8192, 256, 0, stream>>>(x, x16, 4096 * 2048);
  castT<<<dim3(48, 64), 256, 0, stream>>>(wqd, bqd, 2048, 1536);
  castT<<<dim3(64, 48), 256, 0, stream>>>(wqun, bqun, 1536, 2048);
  castT<<<dim3(32, 48), 256, 0, stream>>>(wqur, bqur, 1536, 1024);
  castT<<<dim3(20, 64), 256, 0, stream>>>(wkvd, bkvd, 2048, 576);
  castT<<<dim3(128, 16), 256, 0, stream>>>(wkvu, bkvu, 512, 4096);
  castT<<<dim3(64, 64), 256, 0, stream>>>(wwo, bwo, 2048, 2048);

  gemm_bt<<<dim3(12, 32), 256, 0, stream>>>(x16, bqd, cq, 4096, 1536, 2048, 0);
  rmsnorm_rows<<<4096, 256, 0, stream>>>(cq, cq, qnw, 1536, 1536, 1536);
  gemm_bt<<<dim3(16, 32), 256, 0, stream>>>(cq, bqun, qn, 4096, 2048, 1536, 0);
  gemm_bt<<<dim3(8, 32), 256, 0, stream>>>(cq, bqur, qr, 4096, 1024, 1536, 0);
  gemm_bt<<<dim3(5, 32), 256, 0, stream>>>(x16, bkvd, kvr, 4096, 640, 2048, 0);
  rmsnorm_rows<<<4096, 256, 0, stream>>>(kvr, ckv, kvnw, 512, 640, 512);
  gemm_bt<<<dim3(32, 32), 256, 0, stream>>>(ckv, bkvu, kvu, 4096, 4096, 512, 0);
  qpack<<<16384, 256, 0, stream>>>(qn, qr, qhnw, fcos, fsin, qp);
  kvpack<<<1024, 256, 0, stream>>>(kvu, kvr, khnw, fcos, fsin, kp, vp);
  attn_kernel<<<dim3(32, 32), 256, 0, stream>>>(qp, kp, vp, ao);
  gemm_bt<<<dim3(16, 32), 256, 0, stream>>>(ao, bwo, out, 4096, 2048, 2048, 1);
}

// Round 2
// 675.000 us; speedup vs baseline: 1.1055x; 1.1055x over previous
//
#include <hip/hip_runtime.h>
#include <hip/hip_bf16.h>
#include <stdint.h>

typedef unsigned short u16;
typedef __bf16 bf16x8 __attribute__((ext_vector_type(8)));
typedef __attribute__((ext_vector_type(4))) float f32x4;
typedef __attribute__((ext_vector_type(4))) unsigned short u16x4;
typedef __attribute__((ext_vector_type(4))) int i32x4;

#define T_ 2048

__device__ __forceinline__ u16 f2bf(float f) {
  __hip_bfloat16 h = __float2bfloat16(f);
  return __builtin_bit_cast(u16, h);
}
__device__ __forceinline__ float bf2f(u16 u) {
  __hip_bfloat16 h = __builtin_bit_cast(__hip_bfloat16, u);
  return __bfloat162float(h);
}
// async global->LDS, 16B per lane. lds ptr must be wave-uniform base; lane i
// lands at base + i*16.
__device__ __forceinline__ void g2l16(const void* g, void* l) {
  __builtin_amdgcn_global_load_lds(
      (const __attribute__((address_space(1))) void*)g,
      (__attribute__((address_space(3))) void*)l, 16, 0, 0);
}

// ---------------- casts ----------------
__global__ __launch_bounds__(256) void cast_f32_bf16(const float* __restrict__ in,
                                                     u16* __restrict__ outp, int n) {
  int i = (blockIdx.x * 256 + threadIdx.x) * 4;
  if (i < n) {
    f32x4 v = *(const f32x4*)(in + i);
    u16x4 o;
    o.x = f2bf(v.x); o.y = f2bf(v.y); o.z = f2bf(v.z); o.w = f2bf(v.w);
    *(u16x4*)(outp + i) = o;
  }
}

// in fp32 [R][C] -> out bf16 [Cpad][R]; cols >= C write 0 (zero padding rows).
__global__ __launch_bounds__(256) void castT(const float* __restrict__ in,
                                             u16* __restrict__ outp, int R, int C) {
  __shared__ float tile[32][33];
  int tx = threadIdx.x & 31, ty = threadIdx.x >> 5;  // ty 0..7
  int r0 = blockIdx.y * 32, c0 = blockIdx.x * 32;
#pragma unroll
  for (int p = 0; p < 4; p++) {
    int rr = r0 + ty + p * 8;
    int cc = c0 + tx;
    tile[ty + p * 8][tx] = (cc < C) ? in[(size_t)rr * C + cc] : 0.f;
  }
  __syncthreads();
#pragma unroll
  for (int p = 0; p < 4; p++) {
    outp[(size_t)(c0 + ty + p * 8) * R + r0 + tx] = f2bf(tile[tx][ty + p * 8]);
  }
}

// ---------------- rmsnorm over rows ----------------
__global__ __launch_bounds__(256) void rmsnorm_rows(const u16* __restrict__ in,
                                                    u16* __restrict__ outp,
                                                    const float* __restrict__ w,
                                                    int D, int sin, int sout) {
  int r = blockIdx.x, tid = threadIdx.x;
  int wave = tid >> 6, lane = tid & 63;
  __shared__ float sred[4];
  float vals[6];
  int E = D >> 8;
  float ss = 0.f;
  for (int e = 0; e < E; e++) {
    float v = bf2f(in[(size_t)r * sin + e * 256 + tid]);
    vals[e] = v;
    ss += v * v;
  }
#pragma unroll
  for (int d = 1; d < 64; d <<= 1) ss += __shfl_xor(ss, d, 64);
  if (lane == 0) sred[wave] = ss;
  __syncthreads();
  ss = sred[0] + sred[1] + sred[2] + sred[3];
  float rr = rsqrtf(ss / (float)D + 1e-6f);
  for (int e = 0; e < E; e++)
    outp[(size_t)r * sout + e * 256 + tid] = f2bf(vals[e] * rr * w[e * 256 + tid]);
}

// ---------------- GEMM: C[M,N] = A[M,K] * Bt[N,K]^T  (bf16 in, fp32 acc) ----
__global__ __launch_bounds__(256) void gemm_bt(const u16* __restrict__ A,
                                               const u16* __restrict__ Bt,
                                               void* __restrict__ Cv,
                                               int M, int N, int K, int cf32) {
  __shared__ u16 As[128 * 32];
  __shared__ u16 Bs[128 * 32];
  const int tid = threadIdx.x;
  const int wave = tid >> 6, lane = tid & 63;
  const int m0 = blockIdx.y * 128, n0 = blockIdx.x * 128;
  const int wm = (wave >> 1) * 64, wn = (wave & 1) * 64;
  const int fr = lane & 15, fq = lane >> 4;
  f32x4 acc[4][4] = {};
  const int L = tid * 16;
  const int r0 = L >> 6;
  const int ce = (L & 63) >> 1;
  const u16* ap = A + (size_t)(m0 + r0) * K + ce;
  const u16* bp = Bt + (size_t)(n0 + r0) * K + ce;
  u16* asd = As + wave * 512;
  u16* bsd = Bs + wave * 512;
  for (int k0 = 0; k0 < K; k0 += 32) {
    g2l16(ap + k0, asd);
    g2l16(ap + (size_t)64 * K + k0, asd + 2048);
    g2l16(bp + k0, bsd);
    g2l16(bp + (size_t)64 * K + k0, bsd + 2048);
    __syncthreads();
    bf16x8 af[4], bf[4];
#pragma unroll
    for (int i = 0; i < 4; i++) {
      af[i] = *(const bf16x8*)(As + (wm + 16 * i + fr) * 32 + fq * 8);
      bf[i] = *(const bf16x8*)(Bs + (wn + 16 * i + fr) * 32 + fq * 8);
    }
#pragma unroll
    for (int i = 0; i < 4; i++)
#pragma unroll
      for (int j = 0; j < 4; j++)
        acc[i][j] = __builtin_amdgcn_mfma_f32_16x16x32_bf16(af[i], bf[j], acc[i][j], 0, 0, 0);
    __syncthreads();
  }
  if (cf32) {
    float* C = (float*)Cv;
#pragma unroll
    for (int i = 0; i < 4; i++)
#pragma unroll
      for (int j = 0; j < 4; j++)
#pragma unroll
        for (int r = 0; r < 4; r++)
          C[(size_t)(m0 + wm + 16 * i + fq * 4 + r) * N + n0 + wn + 16 * j + fr] = acc[i][j][r];
  } else {
    u16* C = (u16*)Cv;
#pragma unroll
    for (int i = 0; i < 4; i++)
#pragma unroll
      for (int j = 0; j < 4; j++)
#pragma unroll
        for (int r = 0; r < 4; r++)
          C[(size_t)(m0 + wm + 16 * i + fq * 4 + r) * N + n0 + wn + 16 * j + fr] = f2bf(acc[i][j][r]);
  }
}

// ---------------- q pack: head rmsnorm + rope + 1/sqrt(192) scale ----------
// qnr: [4096][3072] (nope 0..2047, rope 2048..3071) -> qp[bh][t][192]
__global__ __launch_bounds__(256) void qpack(const u16* __restrict__ qnr,
                                             const float* __restrict__ qhw,
                                             const float* __restrict__ fcos,
                                             const float* __restrict__ fsin,
                                             u16* __restrict__ qp) {
  int gw = blockIdx.x * 4 + (threadIdx.x >> 6);
  int lane = threadIdx.x & 63;
  int r = gw >> 4, h = gw & 15;
  int b = r >> 11, t = r & 2047;
  const float sc = 0.07216878364870323f;  // 1/sqrt(192), folded into Q
  float v0 = bf2f(qnr[(size_t)r * 3072 + h * 128 + lane]);
  float v1 = bf2f(qnr[(size_t)r * 3072 + h * 128 + 64 + lane]);
  float ss = v0 * v0 + v1 * v1;
#pragma unroll
  for (int d = 1; d < 64; d <<= 1) ss += __shfl_xor(ss, d, 64);
  float rr = rsqrtf(ss * (1.f / 128.f) + 1e-6f) * sc;
  size_t ob = ((size_t)(b * 16 + h) * 2048 + t) * 192;
  qp[ob + lane] = f2bf(v0 * rr * qhw[lane]);
  qp[ob + 64 + lane] = f2bf(v1 * rr * qhw[64 + lane]);
  if (lane < 32) {
    float a = bf2f(qnr[(size_t)r * 3072 + 2048 + h * 64 + 2 * lane]);
    float bb = bf2f(qnr[(size_t)r * 3072 + 2048 + h * 64 + 2 * lane + 1]);
    float c = fcos[t * 32 + lane], s = fsin[t * 32 + lane];
    qp[ob + 128 + 2 * lane] = f2bf((a * c - bb * s) * sc);
    qp[ob + 129 + 2 * lane] = f2bf((a * s + bb * c) * sc);
  }
}

// ---------------- kv pack: k head-norm + rope bcast; V tile-transpose ------
__global__ __launch_bounds__(256) void kvpack(const u16* __restrict__ kvu,
                                              const u16* __restrict__ kvr,
                                              const float* __restrict__ khw,
                                              const float* __restrict__ fcos,
                                              const float* __restrict__ fsin,
                                              u16* __restrict__ kp,
                                              u16* __restrict__ vp) {
  int h = blockIdx.x & 15, tile = blockIdx.x >> 4;
  int r0 = tile * 64;
  int b = r0 >> 11;
  int tl = tile & 31;
  int tid = threadIdx.x, wave = tid >> 6, lane = tid & 63;
  __shared__ u16 vsl[128 * 66];
  int bh = b * 16 + h;
  for (int ii = 0; ii < 16; ii++) {
    int i = wave * 16 + ii;
    int r = r0 + i;
    int t = r & 2047;
    size_t kbase = (size_t)r * 4096 + h * 256;
    float v0 = bf2f(kvu[kbase + lane]);
    float v1 = bf2f(kvu[kbase + 64 + lane]);
    float ss = v0 * v0 + v1 * v1;
#pragma unroll
    for (int d = 1; d < 64; d <<= 1) ss += __shfl_xor(ss, d, 64);
    float rr = rsqrtf(ss * (1.f / 128.f) + 1e-6f);
    size_t ob = ((size_t)bh * 2048 + t) * 192;
    kp[ob + lane] = f2bf(v0 * rr * khw[lane]);
    kp[ob + 64 + lane] = f2bf(v1 * rr * khw[64 + lane]);
    vsl[lane * 66 + i] = kvu[kbase + 128 + lane];
    vsl[(lane + 64) * 66 + i] = kvu[kbase + 192 + lane];
    if (lane < 32) {
      float a = bf2f(kvr[(size_t)r * 640 + 512 + 2 * lane]);
      float bb = bf2f(kvr[(size_t)r * 640 + 512 + 2 * lane + 1]);
      float c = fcos[t * 32 + lane], s = fsin[t * 32 + lane];
      kp[ob + 128 + 2 * lane] = f2bf(a * c - bb * s);
      kp[ob + 129 + 2 * lane] = f2bf(a * s + bb * c);
    }
  }
  __syncthreads();
  u16* vb = vp + ((size_t)bh * 32 + tl) * 8192;  // [128][64] tile
  for (int u = 0; u < 32; u++) {
    int e = u * 256 + tid;
    vb[e] = vsl[(e >> 6) * 66 + (e & 63)];
  }
}

// ---------------- flash attention (causal) ---------------------------------
// Q,K: [BH][T][192] (Q pre-scaled); Vt: [BH][T/64][128][64]; O: [B*T][2048]
// Register-prefetch pipeline: tile j+1 loads to VGPRs during compute of j.
// Padded LDS rows (K 400B, V/P 144B) -> 2-way-max bank aliasing (free).
__global__ __launch_bounds__(256, 3) void attn_kernel(const u16* __restrict__ Q,
                                                      const u16* __restrict__ Kp,
                                                      const u16* __restrict__ Vt,
                                                      u16* __restrict__ O) {
  __shared__ u16 Ks[64 * 200];   // 64 rows x 192 data + 4 pad (400B stride)
  __shared__ u16 Vs[128 * 72];   // 128 rows x 64 data + 8 pad (144B stride)
  __shared__ u16 Ps[4][16 * 72]; // per-wave P, 144B row stride
  const int tid = threadIdx.x;
  const int wave = tid >> 6, lane = tid & 63;
  const int bh = blockIdx.y;
  const int qt = (int)gridDim.x - 1 - (int)blockIdx.x;  // heavy blocks first
  const int fr = lane & 15, fq = lane >> 4;
  const int myq = qt * 64 + wave * 16 + fr;

  bf16x8 qf[6];
  {
    const u16* qb = Q + ((size_t)bh * T_ + myq) * 192 + fq * 8;
#pragma unroll
    for (int c = 0; c < 6; c++) qf[c] = *(const bf16x8*)(qb + c * 32);
  }
  f32x4 o[8] = {};
  float m_i[4], l_i[4];
#pragma unroll
  for (int r = 0; r < 4; r++) { m_i[r] = -3.0e38f; l_i[r] = 0.f; }

  const char* kgb = (const char*)(Kp + (size_t)bh * T_ * 192);
  const char* vgb = (const char*)(Vt + (size_t)bh * 32 * 8192);
  // loop-invariant LDS write addresses (padded layout)
  char* kw[6];
  char* vw[4];
#pragma unroll
  for (int c = 0; c < 6; c++) {
    int fo = c * 4096 + tid * 16;            // flat offset in unpadded tile
    int row = ((fo >> 7) * 43691) >> 17;     // fo / 384
    kw[c] = (char*)Ks + row * 400 + (fo - row * 384);
  }
#pragma unroll
  for (int c = 0; c < 4; c++) {
    int fo = c * 4096 + tid * 16;
    vw[c] = (char*)Vs + (fo >> 7) * 144 + (fo & 127);
  }
  i32x4 kreg[6], vreg[4];
#pragma unroll
  for (int c = 0; c < 6; c++) kreg[c] = *(const i32x4*)(kgb + c * 4096 + tid * 16);
#pragma unroll
  for (int c = 0; c < 4; c++) vreg[c] = *(const i32x4*)(vgb + c * 4096 + tid * 16);

  for (int j = 0; j <= qt; j++) {
    if (j) __syncthreads();  // all waves done reading previous tile
#pragma unroll
    for (int c = 0; c < 6; c++) *(i32x4*)kw[c] = kreg[c];
#pragma unroll
    for (int c = 0; c < 4; c++) *(i32x4*)vw[c] = vreg[c];
    __syncthreads();         // staging visible
    if (j < qt) {            // prefetch next tile; latency hidden by compute
      const char* kg = kgb + (size_t)(j + 1) * 24576;
      const char* vg = vgb + (size_t)(j + 1) * 16384;
#pragma unroll
      for (int c = 0; c < 6; c++) kreg[c] = *(const i32x4*)(kg + c * 4096 + tid * 16);
#pragma unroll
      for (int c = 0; c < 4; c++) vreg[c] = *(const i32x4*)(vg + c * 4096 + tid * 16);
    }

    // S = Q K^T (Q pre-scaled by 1/sqrt(192))
    f32x4 s[4] = {};
#pragma unroll
    for (int ni = 0; ni < 4; ni++) {
      const u16* kb = Ks + (16 * ni + fr) * 200 + fq * 8;
#pragma unroll
      for (int c = 0; c < 6; c++) {
        bf16x8 kf = *(const bf16x8*)(kb + c * 32);
        s[ni] = __builtin_amdgcn_mfma_f32_16x16x32_bf16(qf[c], kf, s[ni], 0, 0, 0);
      }
    }
    const int qg0 = qt * 64 + wave * 16 + fq * 4;
#pragma unroll
    for (int r = 0; r < 4; r++) {
      if (j == qt) {
#pragma unroll
        for (int ni = 0; ni < 4; ni++)
          if (j * 64 + ni * 16 + fr > qg0 + r) s[ni][r] = -3.0e38f;
      }
      float mx = fmaxf(fmaxf(s[0][r], s[1][r]), fmaxf(s[2][r], s[3][r]));
#pragma unroll
      for (int d = 1; d < 16; d <<= 1) mx = fmaxf(mx, __shfl_xor(mx, d, 64));
      float mn = fmaxf(m_i[r], mx);
      float al = exp2f((m_i[r] - mn) * 1.44269504f);
      float rs = 0.f;
#pragma unroll
      for (int ni = 0; ni < 4; ni++) {
        float p = exp2f((s[ni][r] - mn) * 1.44269504f);
        s[ni][r] = p;
        rs += p;
      }
#pragma unroll
      for (int d = 1; d < 16; d <<= 1) rs += __shfl_xor(rs, d, 64);
      m_i[r] = mn;
      l_i[r] = l_i[r] * al + rs;
#pragma unroll
      for (int ti = 0; ti < 8; ti++) o[ti][r] *= al;
    }
    // P: C-layout -> per-wave LDS -> A-layout (no barrier needed: wave-local)
    u16* pw = Ps[wave];
#pragma unroll
    for (int ni = 0; ni < 4; ni++)
#pragma unroll
      for (int r = 0; r < 4; r++)
        pw[(fq * 4 + r) * 72 + ni * 16 + fr] = f2bf(s[ni][r]);
    __asm__ __volatile__("s_waitcnt lgkmcnt(0)" ::: "memory");
    // O += P V
#pragma unroll
    for (int c = 0; c < 2; c++) {
      bf16x8 pf = *(const bf16x8*)(pw + fr * 72 + c * 32 + fq * 8);
#pragma unroll
      for (int ti = 0; ti < 8; ti++) {
        bf16x8 vf = *(const bf16x8*)(Vs + (16 * ti + fr) * 72 + c * 32 + fq * 8);
        o[ti] = __builtin_amdgcn_mfma_f32_16x16x32_bf16(pf, vf, o[ti], 0, 0, 0);
      }
    }
  }
  const int b = bh >> 4, h = bh & 15;
#pragma unroll
  for (int r = 0; r < 4; r++) {
    float inv = 1.f / l_i[r];
    int q = qt * 64 + wave * 16 + fq * 4 + r;
    u16* orow = O + ((size_t)(b * T_ + q)) * 2048 + h * 128 + fr;
#pragma unroll
    for (int ti = 0; ti < 8; ti++) orow[ti * 16] = f2bf(o[ti][r] * inv);
  }
}

extern "C" void kernel_launch(void* const* d_in, const int* in_sizes, int n_in,
                              void* d_out, int out_size, void* d_ws, size_t ws_size,
                              hipStream_t stream) {
  const float* x    = (const float*)d_in[0];
  const float* fcos = (const float*)d_in[1];
  const float* fsin = (const float*)d_in[2];
  const float* wqd  = (const float*)d_in[3];
  const float* qnw  = (const float*)d_in[4];
  const float* wqun = (const float*)d_in[5];
  const float* wqur = (const float*)d_in[6];
  const float* wkvd = (const float*)d_in[7];
  const float* kvnw = (const float*)d_in[8];
  const float* wkvu = (const float*)d_in[9];
  const float* qhnw = (const float*)d_in[10];
  const float* khnw = (const float*)d_in[11];
  const float* wwo  = (const float*)d_in[12];
  float* out = (float*)d_out;
  char* ws = (char*)d_ws;

  size_t off = 0;
  auto alloc = [&](size_t elems) -> u16* {
    u16* p = (u16*)(ws + off);
    off += ((elems * 2 + 255) & ~(size_t)255);
    return p;
  };
  u16* x16  = alloc(4096ull * 2048);
  u16* bqd  = alloc(1536ull * 2048);
  u16* bqu  = alloc(3072ull * 1536);  // merged q_up: [3072 N][1536 K]
  u16* bkvd = alloc(640ull * 2048);
  u16* bkvu = alloc(4096ull * 512);
  u16* bwo  = alloc(2048ull * 2048);
  u16* cq   = alloc(4096ull * 1536);
  u16* qnr  = alloc(4096ull * 3072);  // merged q_up output
  u16* kvr  = alloc(4096ull * 640);
  u16* ckv  = alloc(4096ull * 512);
  u16* kvu  = alloc(4096ull * 4096);
  u16* qp   = alloc(32ull * 2048 * 192);
  u16* kp   = alloc(32ull * 2048 * 192);
  u16* vp   = alloc(32ull * 2048 * 128);
  u16* ao   = alloc(4096ull * 2048);
  if (ws_size < off) return;

  cast_f32_bf16<<<8192, 256, 0, stream>>>(x, x16, 4096 * 2048);
  castT<<<dim3(48, 64), 256, 0, stream>>>(wqd, bqd, 2048, 1536);
  castT<<<dim3(64, 48), 256, 0, stream>>>(wqun, bqu, 1536, 2048);
  castT<<<dim3(32, 48), 256, 0, stream>>>(wqur, bqu + 2048ull * 1536, 1536, 1024);
  castT<<<dim3(20, 64), 256, 0, stream>>>(wkvd, bkvd, 2048, 576);
  castT<<<dim3(128, 16), 256, 0, stream>>>(wkvu, bkvu, 512, 4096);
  castT<<<dim3(64, 64), 256, 0, stream>>>(wwo, bwo, 2048, 2048);

  gemm_bt<<<dim3(12, 32), 256, 0, stream>>>(x16, bqd, cq, 4096, 1536, 2048, 0);
  rmsnorm_rows<<<4096, 256, 0, stream>>>(cq, cq, qnw, 1536, 1536, 1536);
  gemm_bt<<<dim3(24, 32), 256, 0, stream>>>(cq, bqu, qnr, 4096, 3072, 1536, 0);
  gemm_bt<<<dim3(5, 32), 256, 0, stream>>>(x16, bkvd, kvr, 4096, 640, 2048, 0);
  rmsnorm_rows<<<4096, 256, 0, stream>>>(kvr, ckv, kvnw, 512, 640, 512);
  gemm_bt<<<dim3(32, 32), 256, 0, stream>>>(ckv, bkvu, kvu, 4096, 4096, 512, 0);
  qpack<<<16384, 256, 0, stream>>>(qnr, qhnw, fcos, fsin, qp);
  kvpack<<<1024, 256, 0, stream>>>(kvu, kvr, khnw, fcos, fsin, kp, vp);
  attn_kernel<<<dim3(32, 32), 256, 0, stream>>>(qp, kp, vp, ao);
  gemm_bt<<<dim3(16, 32), 256, 0, stream>>>(ao, bwo, out, 4096, 2048, 2048, 1);
}

// Round 3
// 569.670 us; speedup vs baseline: 1.3099x; 1.1849x over previous
//
#include <hip/hip_runtime.h>
#include <hip/hip_bf16.h>
#include <stdint.h>

typedef unsigned short u16;
typedef __bf16 bf16x8 __attribute__((ext_vector_type(8)));
typedef __attribute__((ext_vector_type(4))) float f32x4;
typedef __attribute__((ext_vector_type(16))) float f32x16;
typedef __attribute__((ext_vector_type(4))) unsigned short u16x4;
typedef __attribute__((ext_vector_type(4))) int i32x4;

#define T_ 2048

__device__ __forceinline__ u16 f2bf(float f) {
  __hip_bfloat16 h = __float2bfloat16(f);
  return __builtin_bit_cast(u16, h);
}
__device__ __forceinline__ float bf2f(u16 u) {
  __hip_bfloat16 h = __builtin_bit_cast(__hip_bfloat16, u);
  return __bfloat162float(h);
}
__device__ __forceinline__ unsigned pk2(float a, float b) {
  return (unsigned)f2bf(a) | ((unsigned)f2bf(b) << 16);
}
__device__ __forceinline__ void g2l16(const void* g, void* l) {
  __builtin_amdgcn_global_load_lds(
      (const __attribute__((address_space(1))) void*)g,
      (__attribute__((address_space(3))) void*)l, 16, 0, 0);
}

// ---------------- casts ----------------
__global__ __launch_bounds__(256) void cast_f32_bf16(const float* __restrict__ in,
                                                     u16* __restrict__ outp, int n) {
  int i = (blockIdx.x * 256 + threadIdx.x) * 4;
  if (i < n) {
    f32x4 v = *(const f32x4*)(in + i);
    u16x4 o;
    o.x = f2bf(v.x); o.y = f2bf(v.y); o.z = f2bf(v.z); o.w = f2bf(v.w);
    *(u16x4*)(outp + i) = o;
  }
}

// in fp32 [R][C] -> out bf16 [Cpad][R]; cols >= C write 0 (zero padding rows).
__global__ __launch_bounds__(256) void castT(const float* __restrict__ in,
                                             u16* __restrict__ outp, int R, int C) {
  __shared__ float tile[32][33];
  int tx = threadIdx.x & 31, ty = threadIdx.x >> 5;
  int r0 = blockIdx.y * 32, c0 = blockIdx.x * 32;
#pragma unroll
  for (int p = 0; p < 4; p++) {
    int rr = r0 + ty + p * 8;
    int cc = c0 + tx;
    tile[ty + p * 8][tx] = (cc < C) ? in[(size_t)rr * C + cc] : 0.f;
  }
  __syncthreads();
#pragma unroll
  for (int p = 0; p < 4; p++) {
    outp[(size_t)(c0 + ty + p * 8) * R + r0 + tx] = f2bf(tile[tx][ty + p * 8]);
  }
}

// ---------------- rmsnorm over rows ----------------
__global__ __launch_bounds__(256) void rmsnorm_rows(const u16* __restrict__ in,
                                                    u16* __restrict__ outp,
                                                    const float* __restrict__ w,
                                                    int D, int sin, int sout) {
  int r = blockIdx.x, tid = threadIdx.x;
  int wave = tid >> 6, lane = tid & 63;
  __shared__ float sred[4];
  float vals[6];
  int E = D >> 8;
  float ss = 0.f;
  for (int e = 0; e < E; e++) {
    float v = bf2f(in[(size_t)r * sin + e * 256 + tid]);
    vals[e] = v;
    ss += v * v;
  }
#pragma unroll
  for (int d = 1; d < 64; d <<= 1) ss += __shfl_xor(ss, d, 64);
  if (lane == 0) sred[wave] = ss;
  __syncthreads();
  ss = sred[0] + sred[1] + sred[2] + sred[3];
  float rr = rsqrtf(ss / (float)D + 1e-6f);
  for (int e = 0; e < E; e++)
    outp[(size_t)r * sout + e * 256 + tid] = f2bf(vals[e] * rr * w[e * 256 + tid]);
}

// ---------------- GEMM: C[M,N] = A[M,K] * Bt[N,K]^T  (bf16 in, fp32 acc) ----
__global__ __launch_bounds__(256) void gemm_bt(const u16* __restrict__ A,
                                               const u16* __restrict__ Bt,
                                               void* __restrict__ Cv,
                                               int M, int N, int K, int cf32) {
  __shared__ u16 As[128 * 32];
  __shared__ u16 Bs[128 * 32];
  const int tid = threadIdx.x;
  const int wave = tid >> 6, lane = tid & 63;
  const int m0 = blockIdx.y * 128, n0 = blockIdx.x * 128;
  const int wm = (wave >> 1) * 64, wn = (wave & 1) * 64;
  const int fr = lane & 15, fq = lane >> 4;
  f32x4 acc[4][4] = {};
  const int L = tid * 16;
  const int r0 = L >> 6;
  const int ce = (L & 63) >> 1;
  const u16* ap = A + (size_t)(m0 + r0) * K + ce;
  const u16* bp = Bt + (size_t)(n0 + r0) * K + ce;
  u16* asd = As + wave * 512;
  u16* bsd = Bs + wave * 512;
  for (int k0 = 0; k0 < K; k0 += 32) {
    g2l16(ap + k0, asd);
    g2l16(ap + (size_t)64 * K + k0, asd + 2048);
    g2l16(bp + k0, bsd);
    g2l16(bp + (size_t)64 * K + k0, bsd + 2048);
    __syncthreads();
    bf16x8 af[4], bf[4];
#pragma unroll
    for (int i = 0; i < 4; i++) {
      af[i] = *(const bf16x8*)(As + (wm + 16 * i + fr) * 32 + fq * 8);
      bf[i] = *(const bf16x8*)(Bs + (wn + 16 * i + fr) * 32 + fq * 8);
    }
#pragma unroll
    for (int i = 0; i < 4; i++)
#pragma unroll
      for (int j = 0; j < 4; j++)
        acc[i][j] = __builtin_amdgcn_mfma_f32_16x16x32_bf16(af[i], bf[j], acc[i][j], 0, 0, 0);
    __syncthreads();
  }
  if (cf32) {
    float* C = (float*)Cv;
#pragma unroll
    for (int i = 0; i < 4; i++)
#pragma unroll
      for (int j = 0; j < 4; j++)
#pragma unroll
        for (int r = 0; r < 4; r++)
          C[(size_t)(m0 + wm + 16 * i + fq * 4 + r) * N + n0 + wn + 16 * j + fr] = acc[i][j][r];
  } else {
    u16* C = (u16*)Cv;
#pragma unroll
    for (int i = 0; i < 4; i++)
#pragma unroll
      for (int j = 0; j < 4; j++)
#pragma unroll
        for (int r = 0; r < 4; r++)
          C[(size_t)(m0 + wm + 16 * i + fq * 4 + r) * N + n0 + wn + 16 * j + fr] = f2bf(acc[i][j][r]);
  }
}

// ---------------- q pack: head rmsnorm + rope + 1/sqrt(192) scale ----------
__global__ __launch_bounds__(256) void qpack(const u16* __restrict__ qnr,
                                             const float* __restrict__ qhw,
                                             const float* __restrict__ fcos,
                                             const float* __restrict__ fsin,
                                             u16* __restrict__ qp) {
  int gw = blockIdx.x * 4 + (threadIdx.x >> 6);
  int lane = threadIdx.x & 63;
  int r = gw >> 4, h = gw & 15;
  int b = r >> 11, t = r & 2047;
  const float sc = 0.07216878364870323f;  // 1/sqrt(192), folded into Q
  float v0 = bf2f(qnr[(size_t)r * 3072 + h * 128 + lane]);
  float v1 = bf2f(qnr[(size_t)r * 3072 + h * 128 + 64 + lane]);
  float ss = v0 * v0 + v1 * v1;
#pragma unroll
  for (int d = 1; d < 64; d <<= 1) ss += __shfl_xor(ss, d, 64);
  float rr = rsqrtf(ss * (1.f / 128.f) + 1e-6f) * sc;
  size_t ob = ((size_t)(b * 16 + h) * 2048 + t) * 192;
  qp[ob + lane] = f2bf(v0 * rr * qhw[lane]);
  qp[ob + 64 + lane] = f2bf(v1 * rr * qhw[64 + lane]);
  if (lane < 32) {
    float a = bf2f(qnr[(size_t)r * 3072 + 2048 + h * 64 + 2 * lane]);
    float bb = bf2f(qnr[(size_t)r * 3072 + 2048 + h * 64 + 2 * lane + 1]);
    float c = fcos[t * 32 + lane], s = fsin[t * 32 + lane];
    qp[ob + 128 + 2 * lane] = f2bf((a * c - bb * s) * sc);
    qp[ob + 129 + 2 * lane] = f2bf((a * s + bb * c) * sc);
  }
}

// ---------------- kv pack ----------------
__global__ __launch_bounds__(256) void kvpack(const u16* __restrict__ kvu,
                                              const u16* __restrict__ kvr,
                                              const float* __restrict__ khw,
                                              const float* __restrict__ fcos,
                                              const float* __restrict__ fsin,
                                              u16* __restrict__ kp,
                                              u16* __restrict__ vp) {
  int h = blockIdx.x & 15, tile = blockIdx.x >> 4;
  int r0 = tile * 64;
  int b = r0 >> 11;
  int tl = tile & 31;
  int tid = threadIdx.x, wave = tid >> 6, lane = tid & 63;
  __shared__ u16 vsl[128 * 66];
  int bh = b * 16 + h;
  for (int ii = 0; ii < 16; ii++) {
    int i = wave * 16 + ii;
    int r = r0 + i;
    int t = r & 2047;
    size_t kbase = (size_t)r * 4096 + h * 256;
    float v0 = bf2f(kvu[kbase + lane]);
    float v1 = bf2f(kvu[kbase + 64 + lane]);
    float ss = v0 * v0 + v1 * v1;
#pragma unroll
    for (int d = 1; d < 64; d <<= 1) ss += __shfl_xor(ss, d, 64);
    float rr = rsqrtf(ss * (1.f / 128.f) + 1e-6f);
    size_t ob = ((size_t)bh * 2048 + t) * 192;
    kp[ob + lane] = f2bf(v0 * rr * khw[lane]);
    kp[ob + 64 + lane] = f2bf(v1 * rr * khw[64 + lane]);
    vsl[lane * 66 + i] = kvu[kbase + 128 + lane];
    vsl[(lane + 64) * 66 + i] = kvu[kbase + 192 + lane];
    if (lane < 32) {
      float a = bf2f(kvr[(size_t)r * 640 + 512 + 2 * lane]);
      float bb = bf2f(kvr[(size_t)r * 640 + 512 + 2 * lane + 1]);
      float c = fcos[t * 32 + lane], s = fsin[t * 32 + lane];
      kp[ob + 128 + 2 * lane] = f2bf(a * c - bb * s);
      kp[ob + 129 + 2 * lane] = f2bf(a * s + bb * c);
    }
  }
  __syncthreads();
  u16* vb = vp + ((size_t)bh * 32 + tl) * 8192;  // [128 v][64 t] tile
  for (int u = 0; u < 32; u++) {
    int e = u * 256 + tid;
    vb[e] = vsl[(e >> 6) * 66 + (e & 63)];
  }
}

// ---------------- flash attention (causal), S^T formulation ----------------
// Q,K: [BH][T][192] (Q pre-scaled); Vt: [BH][T/64][128 v][64 t]; O: [B*T][2048]
// Block: 128 q-rows, 4 waves x 32 q. Wave computes S^T[64k x 32q] via
// mfma_32x32x16 (A=K rows, B=Q cols); per-lane softmax over k (2 shuffles);
// O^T[v][q] = V^T * P^T. XOR-swizzled LDS (chunk ^ row&7) -> conflict-free.
__global__ __launch_bounds__(256, 2) void attn_kernel(const u16* __restrict__ Q,
                                                      const u16* __restrict__ Kp,
                                                      const u16* __restrict__ Vt,
                                                      u16* __restrict__ O) {
  __shared__ u16 Ks[64 * 256];   // [64 k-rows][24 used 16B-chunks, 32 slots]
  __shared__ u16 Vs[128 * 64];   // [128 v-rows][8 chunks], swizzled
  __shared__ u16 Ps[4][32 * 64]; // per-wave P^T as P[q][64 k], swizzled
  const int tid = threadIdx.x;
  const int wave = tid >> 6, lane = tid & 63;
  const int bh = blockIdx.y;
  const int qb = (int)gridDim.x - 1 - (int)blockIdx.x;  // heavy blocks first
  const int l31 = lane & 31, half = lane >> 5, xr = lane & 7;
  const int qw0 = qb * 128 + wave * 32;       // first q of this wave
  const int qg = qw0 + l31;                   // this lane's q column
  const int jmax = 2 * qb + 1;

  // Q B-fragments: lane holds Q[qg][16t + 8*half + j], t=0..11
  bf16x8 qf[12];
  {
    const u16* qbp = Q + ((size_t)bh * T_ + qg) * 192 + half * 8;
#pragma unroll
    for (int t = 0; t < 12; t++) qf[t] = *(const bf16x8*)(qbp + t * 16);
  }
  f32x16 oacc[4] = {};
  float m_i = -3.0e38f, l_i = 0.f;

  const char* kgb = (const char*)(Kp + (size_t)bh * T_ * 192);
  const char* vgb = (const char*)(Vt + (size_t)bh * 32 * 8192);
  // loop-invariant swizzled staging addresses (elements)
  u16* kw[6];
  u16* vw[4];
#pragma unroll
  for (int c = 0; c < 6; c++) {
    unsigned fo = c * 4096 + tid * 16;     // byte offset in 24576B K tile
    unsigned row = fo / 384u;
    unsigned chunk = (fo - row * 384) >> 4;
    kw[c] = Ks + row * 256 + ((chunk ^ (row & 7)) << 3);
  }
#pragma unroll
  for (int c = 0; c < 4; c++) {
    unsigned fo = c * 4096 + tid * 16;     // byte offset in 16384B V tile
    unsigned row = fo >> 7;
    unsigned chunk = (fo >> 4) & 7;
    vw[c] = Vs + row * 64 + ((chunk ^ (row & 7)) << 3);
  }
  const u16* krd0 = Ks + l31 * 256;        // k-rows 0..31
  const u16* krd1 = Ks + (32 + l31) * 256; // k-rows 32..63
  const u16* vrd = Vs + l31 * 64;
  u16* pw = Ps[wave];
  const u16* prd = pw + l31 * 64;

  i32x4 kreg[6], vreg[4];
#pragma unroll
  for (int c = 0; c < 6; c++) kreg[c] = *(const i32x4*)(kgb + c * 4096 + tid * 16);
#pragma unroll
  for (int c = 0; c < 4; c++) vreg[c] = *(const i32x4*)(vgb + c * 4096 + tid * 16);

  for (int j = 0; j <= jmax; j++) {
    if (j) __syncthreads();
#pragma unroll
    for (int c = 0; c < 6; c++) *(i32x4*)kw[c] = kreg[c];
#pragma unroll
    for (int c = 0; c < 4; c++) *(i32x4*)vw[c] = vreg[c];
    __syncthreads();
    if (j < jmax) {
      const char* kg = kgb + (size_t)(j + 1) * 24576;
      const char* vg = vgb + (size_t)(j + 1) * 16384;
#pragma unroll
      for (int c = 0; c < 6; c++) kreg[c] = *(const i32x4*)(kg + c * 4096 + tid * 16);
#pragma unroll
      for (int c = 0; c < 4; c++) vreg[c] = *(const i32x4*)(vg + c * 4096 + tid * 16);
    }
    if (j * 64 > qw0 + 31) continue;  // tile fully masked for this wave

    // S^T[64k x 32q]: two 32x32 accs
    f32x16 sa[2] = {};
#pragma unroll
    for (int t = 0; t < 12; t++) {
      int sl = ((2 * t + half) ^ xr) << 3;
      bf16x8 a0 = *(const bf16x8*)(krd0 + sl);
      bf16x8 a1 = *(const bf16x8*)(krd1 + sl);
      sa[0] = __builtin_amdgcn_mfma_f32_32x32x16_bf16(a0, qf[t], sa[0], 0, 0, 0);
      sa[1] = __builtin_amdgcn_mfma_f32_32x32x16_bf16(a1, qf[t], sa[1], 0, 0, 0);
    }
    // causal mask (only needed on the last two tiles of the block)
    if (j * 64 + 63 > qw0) {
      int kb = j * 64 + 4 * half;
#pragma unroll
      for (int tt = 0; tt < 2; tt++)
#pragma unroll
        for (int r = 0; r < 16; r++) {
          int kk = kb + tt * 32 + (r & 3) + 8 * (r >> 2);
          if (kk > qg) sa[tt][r] = -3.0e38f;
        }
    }
    // per-lane softmax over 32 k-values, pair-combine via 1 shuffle each
    float mx = -3.0e38f;
#pragma unroll
    for (int r = 0; r < 16; r++) mx = fmaxf(mx, fmaxf(sa[0][r], sa[1][r]));
    mx = fmaxf(mx, __shfl_xor(mx, 32, 64));
    float mn = fmaxf(m_i, mx);
    float al = exp2f((m_i - mn) * 1.44269504f);
    float rs = 0.f;
#pragma unroll
    for (int tt = 0; tt < 2; tt++)
#pragma unroll
      for (int r = 0; r < 16; r++) {
        float p = exp2f((sa[tt][r] - mn) * 1.44269504f);
        sa[tt][r] = p;
        rs += p;
      }
    rs += __shfl_xor(rs, 32, 64);
    m_i = mn;
    l_i = l_i * al + rs;
#pragma unroll
    for (int vt = 0; vt < 4; vt++)
#pragma unroll
      for (int r = 0; r < 16; r++) oacc[vt][r] *= al;
    // pack P^T -> LDS: rows q, 4 consecutive k per b64 (chunk = 4*tt+qd)
#pragma unroll
    for (int tt = 0; tt < 2; tt++)
#pragma unroll
      for (int qd = 0; qd < 4; qd++) {
        uint2 pk;
        pk.x = pk2(sa[tt][qd * 4 + 0], sa[tt][qd * 4 + 1]);
        pk.y = pk2(sa[tt][qd * 4 + 2], sa[tt][qd * 4 + 3]);
        *(uint2*)(pw + l31 * 64 + (((4 * tt + qd) ^ (l31 & 7)) << 3) + half * 4) = pk;
      }
    __asm__ __volatile__("s_waitcnt lgkmcnt(0)" ::: "memory");
    // O^T += V^T P^T
#pragma unroll
    for (int t = 0; t < 4; t++) {
      bf16x8 pf = *(const bf16x8*)(prd + (((2 * t + half) ^ (l31 & 7)) << 3));
#pragma unroll
      for (int vt = 0; vt < 4; vt++) {
        bf16x8 vf = *(const bf16x8*)(vrd + vt * 32 * 64 + (((2 * t + half) ^ xr) << 3));
        oacc[vt] = __builtin_amdgcn_mfma_f32_32x32x16_bf16(vf, pf, oacc[vt], 0, 0, 0);
      }
    }
  }
  // epilogue: O^T[v][qg] -> O[b*T+qg][h*128+v]
  const int b = bh >> 4, h = bh & 15;
  float inv = 1.f / l_i;
  u16* orow = O + ((size_t)(b * T_ + qg)) * 2048 + h * 128 + 4 * half;
#pragma unroll
  for (int vt = 0; vt < 4; vt++)
#pragma unroll
    for (int qd = 0; qd < 4; qd++) {
      uint2 pk;
      pk.x = pk2(oacc[vt][qd * 4 + 0] * inv, oacc[vt][qd * 4 + 1] * inv);
      pk.y = pk2(oacc[vt][qd * 4 + 2] * inv, oacc[vt][qd * 4 + 3] * inv);
      *(uint2*)(orow + vt * 32 + qd * 8) = pk;
    }
}

extern "C" void kernel_launch(void* const* d_in, const int* in_sizes, int n_in,
                              void* d_out, int out_size, void* d_ws, size_t ws_size,
                              hipStream_t stream) {
  const float* x    = (const float*)d_in[0];
  const float* fcos = (const float*)d_in[1];
  const float* fsin = (const float*)d_in[2];
  const float* wqd  = (const float*)d_in[3];
  const float* qnw  = (const float*)d_in[4];
  const float* wqun = (const float*)d_in[5];
  const float* wqur = (const float*)d_in[6];
  const float* wkvd = (const float*)d_in[7];
  const float* kvnw = (const float*)d_in[8];
  const float* wkvu = (const float*)d_in[9];
  const float* qhnw = (const float*)d_in[10];
  const float* khnw = (const float*)d_in[11];
  const float* wwo  = (const float*)d_in[12];
  float* out = (float*)d_out;
  char* ws = (char*)d_ws;

  size_t off = 0;
  auto alloc = [&](size_t elems) -> u16* {
    u16* p = (u16*)(ws + off);
    off += ((elems * 2 + 255) & ~(size_t)255);
    return p;
  };
  u16* x16  = alloc(4096ull * 2048);
  u16* bqd  = alloc(1536ull * 2048);
  u16* bqu  = alloc(3072ull * 1536);
  u16* bkvd = alloc(640ull * 2048);
  u16* bkvu = alloc(4096ull * 512);
  u16* bwo  = alloc(2048ull * 2048);
  u16* cq   = alloc(4096ull * 1536);
  u16* qnr  = alloc(4096ull * 3072);
  u16* kvr  = alloc(4096ull * 640);
  u16* ckv  = alloc(4096ull * 512);
  u16* kvu  = alloc(4096ull * 4096);
  u16* qp   = alloc(32ull * 2048 * 192);
  u16* kp   = alloc(32ull * 2048 * 192);
  u16* vp   = alloc(32ull * 2048 * 128);
  u16* ao   = alloc(4096ull * 2048);
  if (ws_size < off) return;

  cast_f32_bf16<<<8192, 256, 0, stream>>>(x, x16, 4096 * 2048);
  castT<<<dim3(48, 64), 256, 0, stream>>>(wqd, bqd, 2048, 1536);
  castT<<<dim3(64, 48), 256, 0, stream>>>(wqun, bqu, 1536, 2048);
  castT<<<dim3(32, 48), 256, 0, stream>>>(wqur, bqu + 2048ull * 1536, 1536, 1024);
  castT<<<dim3(20, 64), 256, 0, stream>>>(wkvd, bkvd, 2048, 576);
  castT<<<dim3(128, 16), 256, 0, stream>>>(wkvu, bkvu, 512, 4096);
  castT<<<dim3(64, 64), 256, 0, stream>>>(wwo, bwo, 2048, 2048);

  gemm_bt<<<dim3(12, 32), 256, 0, stream>>>(x16, bqd, cq, 4096, 1536, 2048, 0);
  rmsnorm_rows<<<4096, 256, 0, stream>>>(cq, cq, qnw, 1536, 1536, 1536);
  gemm_bt<<<dim3(24, 32), 256, 0, stream>>>(cq, bqu, qnr, 4096, 3072, 1536, 0);
  gemm_bt<<<dim3(5, 32), 256, 0, stream>>>(x16, bkvd, kvr, 4096, 640, 2048, 0);
  rmsnorm_rows<<<4096, 256, 0, stream>>>(kvr, ckv, kvnw, 512, 640, 512);
  gemm_bt<<<dim3(32, 32), 256, 0, stream>>>(ckv, bkvu, kvu, 4096, 4096, 512, 0);
  qpack<<<16384, 256, 0, stream>>>(qnr, qhnw, fcos, fsin, qp);
  kvpack<<<1024, 256, 0, stream>>>(kvu, kvr, khnw, fcos, fsin, kp, vp);
  attn_kernel<<<dim3(16, 32), 256, 0, stream>>>(qp, kp, vp, ao);
  gemm_bt<<<dim3(16, 32), 256, 0, stream>>>(ao, bwo, out, 4096, 2048, 2048, 1);
}

// Round 4
// 514.923 us; speedup vs baseline: 1.4492x; 1.1063x over previous
//
#include <hip/hip_runtime.h>
#include <hip/hip_bf16.h>
#include <stdint.h>

typedef unsigned short u16;
typedef __bf16 bf16x8 __attribute__((ext_vector_type(8)));
typedef __attribute__((ext_vector_type(4))) float f32x4;
typedef __attribute__((ext_vector_type(16))) float f32x16;
typedef __attribute__((ext_vector_type(4))) unsigned short u16x4;
typedef __attribute__((ext_vector_type(4))) int i32x4;

#define T_ 2048

__device__ __forceinline__ u16 f2bf(float f) {
  __hip_bfloat16 h = __float2bfloat16(f);
  return __builtin_bit_cast(u16, h);
}
__device__ __forceinline__ float bf2f(u16 u) {
  __hip_bfloat16 h = __builtin_bit_cast(__hip_bfloat16, u);
  return __bfloat162float(h);
}
__device__ __forceinline__ unsigned pk2(float a, float b) {
  return (unsigned)f2bf(a) | ((unsigned)f2bf(b) << 16);
}

// ---------------- casts ----------------
__global__ __launch_bounds__(256) void cast_f32_bf16(const float* __restrict__ in,
                                                     u16* __restrict__ outp, int n) {
  int i = (blockIdx.x * 256 + threadIdx.x) * 4;
  if (i < n) {
    f32x4 v = *(const f32x4*)(in + i);
    u16x4 o;
    o.x = f2bf(v.x); o.y = f2bf(v.y); o.z = f2bf(v.z); o.w = f2bf(v.w);
    *(u16x4*)(outp + i) = o;
  }
}

// in fp32 [R][C] -> out bf16 [Cpad][R]; cols >= C write 0 (zero padding rows).
__global__ __launch_bounds__(256) void castT(const float* __restrict__ in,
                                             u16* __restrict__ outp, int R, int C) {
  __shared__ float tile[32][33];
  int tx = threadIdx.x & 31, ty = threadIdx.x >> 5;
  int r0 = blockIdx.y * 32, c0 = blockIdx.x * 32;
#pragma unroll
  for (int p = 0; p < 4; p++) {
    int rr = r0 + ty + p * 8;
    int cc = c0 + tx;
    tile[ty + p * 8][tx] = (cc < C) ? in[(size_t)rr * C + cc] : 0.f;
  }
  __syncthreads();
#pragma unroll
  for (int p = 0; p < 4; p++) {
    outp[(size_t)(c0 + ty + p * 8) * R + r0 + tx] = f2bf(tile[tx][ty + p * 8]);
  }
}

// ---------------- rmsnorm over rows ----------------
__global__ __launch_bounds__(256) void rmsnorm_rows(const u16* __restrict__ in,
                                                    u16* __restrict__ outp,
                                                    const float* __restrict__ w,
                                                    int D, int sin, int sout) {
  int r = blockIdx.x, tid = threadIdx.x;
  int wave = tid >> 6, lane = tid & 63;
  __shared__ float sred[4];
  float vals[6];
  int E = D >> 8;
  float ss = 0.f;
  for (int e = 0; e < E; e++) {
    float v = bf2f(in[(size_t)r * sin + e * 256 + tid]);
    vals[e] = v;
    ss += v * v;
  }
#pragma unroll
  for (int d = 1; d < 64; d <<= 1) ss += __shfl_xor(ss, d, 64);
  if (lane == 0) sred[wave] = ss;
  __syncthreads();
  ss = sred[0] + sred[1] + sred[2] + sred[3];
  float rr = rsqrtf(ss / (float)D + 1e-6f);
  for (int e = 0; e < E; e++)
    outp[(size_t)r * sout + e * 256 + tid] = f2bf(vals[e] * rr * w[e * 256 + tid]);
}

// ---------------- GEMM: C[M,N] = A[M,K] * Bt[N,K]^T  (bf16 in, fp32 acc) ----
// Register-prefetch double-buffer (next BK=32 slab in VGPRs during MFMA) +
// XOR-swizzled LDS (chunk ^ ((row+(row>>2))&3)) for conflict-free b128s.
__global__ __launch_bounds__(256) void gemm_bt(const u16* __restrict__ A,
                                               const u16* __restrict__ Bt,
                                               void* __restrict__ Cv,
                                               int M, int N, int K, int cf32) {
  __shared__ u16 As[128 * 32];
  __shared__ u16 Bs[128 * 32];
  const int tid = threadIdx.x;
  const int wave = tid >> 6, lane = tid & 63;
  const int m0 = blockIdx.y * 128, n0 = blockIdx.x * 128;
  const int wm = (wave >> 1) * 64, wn = (wave & 1) * 64;
  const int fr = lane & 15, fq = lane >> 4;
  f32x4 acc[4][4] = {};

  // staging geometry: thread owns 16B at rows r0a and r0a+64, col ce
  const int r0a = tid >> 2;
  const int ce = (tid & 3) * 8;
  const int sw0 = ((tid & 3) ^ ((r0a + (r0a >> 2)) & 3)) << 3;
  const u16* apg = A + (size_t)(m0 + r0a) * K + ce;
  const u16* bpg = Bt + (size_t)(n0 + r0a) * K + ce;
  u16* aw0 = As + r0a * 32 + sw0;
  u16* bw0 = Bs + r0a * 32 + sw0;

  // loop-invariant fragment read pointers
  const u16* ard[4];
  const u16* brd[4];
#pragma unroll
  for (int i = 0; i < 4; i++) {
    int ra = wm + 16 * i + fr;
    ard[i] = As + ra * 32 + ((fq ^ ((ra + (ra >> 2)) & 3)) << 3);
    int rb = wn + 16 * i + fr;
    brd[i] = Bs + rb * 32 + ((fq ^ ((rb + (rb >> 2)) & 3)) << 3);
  }

  i32x4 a0 = *(const i32x4*)(apg);
  i32x4 a1 = *(const i32x4*)(apg + (size_t)64 * K);
  i32x4 b0 = *(const i32x4*)(bpg);
  i32x4 b1 = *(const i32x4*)(bpg + (size_t)64 * K);

  for (int k0 = 0; k0 < K; k0 += 32) {
    if (k0) __syncthreads();
    *(i32x4*)aw0 = a0;
    *(i32x4*)(aw0 + 64 * 32) = a1;
    *(i32x4*)bw0 = b0;
    *(i32x4*)(bw0 + 64 * 32) = b1;
    __syncthreads();
    if (k0 + 32 < K) {
      a0 = *(const i32x4*)(apg + k0 + 32);
      a1 = *(const i32x4*)(apg + (size_t)64 * K + k0 + 32);
      b0 = *(const i32x4*)(bpg + k0 + 32);
      b1 = *(const i32x4*)(bpg + (size_t)64 * K + k0 + 32);
    }
    bf16x8 af[4], bf[4];
#pragma unroll
    for (int i = 0; i < 4; i++) {
      af[i] = *(const bf16x8*)ard[i];
      bf[i] = *(const bf16x8*)brd[i];
    }
#pragma unroll
    for (int i = 0; i < 4; i++)
#pragma unroll
      for (int j = 0; j < 4; j++)
        acc[i][j] = __builtin_amdgcn_mfma_f32_16x16x32_bf16(af[i], bf[j], acc[i][j], 0, 0, 0);
  }
  if (cf32) {
    float* C = (float*)Cv;
#pragma unroll
    for (int i = 0; i < 4; i++)
#pragma unroll
      for (int j = 0; j < 4; j++)
#pragma unroll
        for (int r = 0; r < 4; r++)
          C[(size_t)(m0 + wm + 16 * i + fq * 4 + r) * N + n0 + wn + 16 * j + fr] = acc[i][j][r];
  } else {
    u16* C = (u16*)Cv;
#pragma unroll
    for (int i = 0; i < 4; i++)
#pragma unroll
      for (int j = 0; j < 4; j++)
#pragma unroll
        for (int r = 0; r < 4; r++)
          C[(size_t)(m0 + wm + 16 * i + fq * 4 + r) * N + n0 + wn + 16 * j + fr] = f2bf(acc[i][j][r]);
  }
}

// ---------------- q pack: head rmsnorm + rope + 1/sqrt(192) scale ----------
__global__ __launch_bounds__(256) void qpack(const u16* __restrict__ qnr,
                                             const float* __restrict__ qhw,
                                             const float* __restrict__ fcos,
                                             const float* __restrict__ fsin,
                                             u16* __restrict__ qp) {
  int gw = blockIdx.x * 4 + (threadIdx.x >> 6);
  int lane = threadIdx.x & 63;
  int r = gw >> 4, h = gw & 15;
  int b = r >> 11, t = r & 2047;
  const float sc = 0.07216878364870323f;  // 1/sqrt(192), folded into Q
  float v0 = bf2f(qnr[(size_t)r * 3072 + h * 128 + lane]);
  float v1 = bf2f(qnr[(size_t)r * 3072 + h * 128 + 64 + lane]);
  float ss = v0 * v0 + v1 * v1;
#pragma unroll
  for (int d = 1; d < 64; d <<= 1) ss += __shfl_xor(ss, d, 64);
  float rr = rsqrtf(ss * (1.f / 128.f) + 1e-6f) * sc;
  size_t ob = ((size_t)(b * 16 + h) * 2048 + t) * 192;
  qp[ob + lane] = f2bf(v0 * rr * qhw[lane]);
  qp[ob + 64 + lane] = f2bf(v1 * rr * qhw[64 + lane]);
  if (lane < 32) {
    float a = bf2f(qnr[(size_t)r * 3072 + 2048 + h * 64 + 2 * lane]);
    float bb = bf2f(qnr[(size_t)r * 3072 + 2048 + h * 64 + 2 * lane + 1]);
    float c = fcos[t * 32 + lane], s = fsin[t * 32 + lane];
    qp[ob + 128 + 2 * lane] = f2bf((a * c - bb * s) * sc);
    qp[ob + 129 + 2 * lane] = f2bf((a * s + bb * c) * sc);
  }
}

// ---------------- kv pack ----------------
// kvr points at the kv_raw section of the fused down-proj output (row stride ks)
__global__ __launch_bounds__(256) void kvpack(const u16* __restrict__ kvu,
                                              const u16* __restrict__ kvr,
                                              int ks,
                                              const float* __restrict__ khw,
                                              const float* __restrict__ fcos,
                                              const float* __restrict__ fsin,
                                              u16* __restrict__ kp,
                                              u16* __restrict__ vp) {
  int h = blockIdx.x & 15, tile = blockIdx.x >> 4;
  int r0 = tile * 64;
  int b = r0 >> 11;
  int tl = tile & 31;
  int tid = threadIdx.x, wave = tid >> 6, lane = tid & 63;
  __shared__ u16 vsl[128 * 66];
  int bh = b * 16 + h;
  for (int ii = 0; ii < 16; ii++) {
    int i = wave * 16 + ii;
    int r = r0 + i;
    int t = r & 2047;
    size_t kbase = (size_t)r * 4096 + h * 256;
    float v0 = bf2f(kvu[kbase + lane]);
    float v1 = bf2f(kvu[kbase + 64 + lane]);
    float ss = v0 * v0 + v1 * v1;
#pragma unroll
    for (int d = 1; d < 64; d <<= 1) ss += __shfl_xor(ss, d, 64);
    float rr = rsqrtf(ss * (1.f / 128.f) + 1e-6f);
    size_t ob = ((size_t)bh * 2048 + t) * 192;
    kp[ob + lane] = f2bf(v0 * rr * khw[lane]);
    kp[ob + 64 + lane] = f2bf(v1 * rr * khw[64 + lane]);
    vsl[lane * 66 + i] = kvu[kbase + 128 + lane];
    vsl[(lane + 64) * 66 + i] = kvu[kbase + 192 + lane];
    if (lane < 32) {
      float a = bf2f(kvr[(size_t)r * ks + 512 + 2 * lane]);
      float bb = bf2f(kvr[(size_t)r * ks + 512 + 2 * lane + 1]);
      float c = fcos[t * 32 + lane], s = fsin[t * 32 + lane];
      kp[ob + 128 + 2 * lane] = f2bf(a * c - bb * s);
      kp[ob + 129 + 2 * lane] = f2bf(a * s + bb * c);
    }
  }
  __syncthreads();
  u16* vb = vp + ((size_t)bh * 32 + tl) * 8192;  // [128 v][64 t] tile
  for (int u = 0; u < 32; u++) {
    int e = u * 256 + tid;
    vb[e] = vsl[(e >> 6) * 66 + (e & 63)];
  }
}

// ---------------- flash attention (causal), S^T formulation ----------------
__global__ __launch_bounds__(256, 2) void attn_kernel(const u16* __restrict__ Q,
                                                      const u16* __restrict__ Kp,
                                                      const u16* __restrict__ Vt,
                                                      u16* __restrict__ O) {
  __shared__ u16 Ks[64 * 256];
  __shared__ u16 Vs[128 * 64];
  __shared__ u16 Ps[4][32 * 64];
  const int tid = threadIdx.x;
  const int wave = tid >> 6, lane = tid & 63;
  const int bh = blockIdx.y;
  const int qb = (int)gridDim.x - 1 - (int)blockIdx.x;
  const int l31 = lane & 31, half = lane >> 5, xr = lane & 7;
  const int qw0 = qb * 128 + wave * 32;
  const int qg = qw0 + l31;
  const int jmax = 2 * qb + 1;

  bf16x8 qf[12];
  {
    const u16* qbp = Q + ((size_t)bh * T_ + qg) * 192 + half * 8;
#pragma unroll
    for (int t = 0; t < 12; t++) qf[t] = *(const bf16x8*)(qbp + t * 16);
  }
  f32x16 oacc[4] = {};
  float m_i = -3.0e38f, l_i = 0.f;

  const char* kgb = (const char*)(Kp + (size_t)bh * T_ * 192);
  const char* vgb = (const char*)(Vt + (size_t)bh * 32 * 8192);
  u16* kw[6];
  u16* vw[4];
#pragma unroll
  for (int c = 0; c < 6; c++) {
    unsigned fo = c * 4096 + tid * 16;
    unsigned row = fo / 384u;
    unsigned chunk = (fo - row * 384) >> 4;
    kw[c] = Ks + row * 256 + ((chunk ^ (row & 7)) << 3);
  }
#pragma unroll
  for (int c = 0; c < 4; c++) {
    unsigned fo = c * 4096 + tid * 16;
    unsigned row = fo >> 7;
    unsigned chunk = (fo >> 4) & 7;
    vw[c] = Vs + row * 64 + ((chunk ^ (row & 7)) << 3);
  }
  const u16* krd0 = Ks + l31 * 256;
  const u16* krd1 = Ks + (32 + l31) * 256;
  const u16* vrd = Vs + l31 * 64;
  u16* pw = Ps[wave];
  const u16* prd = pw + l31 * 64;

  i32x4 kreg[6], vreg[4];
#pragma unroll
  for (int c = 0; c < 6; c++) kreg[c] = *(const i32x4*)(kgb + c * 4096 + tid * 16);
#pragma unroll
  for (int c = 0; c < 4; c++) vreg[c] = *(const i32x4*)(vgb + c * 4096 + tid * 16);

  for (int j = 0; j <= jmax; j++) {
    if (j) __syncthreads();
#pragma unroll
    for (int c = 0; c < 6; c++) *(i32x4*)kw[c] = kreg[c];
#pragma unroll
    for (int c = 0; c < 4; c++) *(i32x4*)vw[c] = vreg[c];
    __syncthreads();
    if (j < jmax) {
      const char* kg = kgb + (size_t)(j + 1) * 24576;
      const char* vg = vgb + (size_t)(j + 1) * 16384;
#pragma unroll
      for (int c = 0; c < 6; c++) kreg[c] = *(const i32x4*)(kg + c * 4096 + tid * 16);
#pragma unroll
      for (int c = 0; c < 4; c++) vreg[c] = *(const i32x4*)(vg + c * 4096 + tid * 16);
    }
    if (j * 64 > qw0 + 31) continue;

    f32x16 sa[2] = {};
#pragma unroll
    for (int t = 0; t < 12; t++) {
      int sl = ((2 * t + half) ^ xr) << 3;
      bf16x8 a0 = *(const bf16x8*)(krd0 + sl);
      bf16x8 a1 = *(const bf16x8*)(krd1 + sl);
      sa[0] = __builtin_amdgcn_mfma_f32_32x32x16_bf16(a0, qf[t], sa[0], 0, 0, 0);
      sa[1] = __builtin_amdgcn_mfma_f32_32x32x16_bf16(a1, qf[t], sa[1], 0, 0, 0);
    }
    if (j * 64 + 63 > qw0) {
      int kb = j * 64 + 4 * half;
#pragma unroll
      for (int tt = 0; tt < 2; tt++)
#pragma unroll
        for (int r = 0; r < 16; r++) {
          int kk = kb + tt * 32 + (r & 3) + 8 * (r >> 2);
          if (kk > qg) sa[tt][r] = -3.0e38f;
        }
    }
    float mx = -3.0e38f;
#pragma unroll
    for (int r = 0; r < 16; r++) mx = fmaxf(mx, fmaxf(sa[0][r], sa[1][r]));
    mx = fmaxf(mx, __shfl_xor(mx, 32, 64));
    float mn = fmaxf(m_i, mx);
    float al = exp2f((m_i - mn) * 1.44269504f);
    float rs = 0.f;
#pragma unroll
    for (int tt = 0; tt < 2; tt++)
#pragma unroll
      for (int r = 0; r < 16; r++) {
        float p = exp2f((sa[tt][r] - mn) * 1.44269504f);
        sa[tt][r] = p;
        rs += p;
      }
    rs += __shfl_xor(rs, 32, 64);
    m_i = mn;
    l_i = l_i * al + rs;
#pragma unroll
    for (int vt = 0; vt < 4; vt++)
#pragma unroll
      for (int r = 0; r < 16; r++) oacc[vt][r] *= al;
#pragma unroll
    for (int tt = 0; tt < 2; tt++)
#pragma unroll
      for (int qd = 0; qd < 4; qd++) {
        uint2 pk;
        pk.x = pk2(sa[tt][qd * 4 + 0], sa[tt][qd * 4 + 1]);
        pk.y = pk2(sa[tt][qd * 4 + 2], sa[tt][qd * 4 + 3]);
        *(uint2*)(pw + l31 * 64 + (((4 * tt + qd) ^ (l31 & 7)) << 3) + half * 4) = pk;
      }
    __asm__ __volatile__("s_waitcnt lgkmcnt(0)" ::: "memory");
#pragma unroll
    for (int t = 0; t < 4; t++) {
      bf16x8 pf = *(const bf16x8*)(prd + (((2 * t + half) ^ (l31 & 7)) << 3));
#pragma unroll
      for (int vt = 0; vt < 4; vt++) {
        bf16x8 vf = *(const bf16x8*)(vrd + vt * 32 * 64 + (((2 * t + half) ^ xr) << 3));
        oacc[vt] = __builtin_amdgcn_mfma_f32_32x32x16_bf16(vf, pf, oacc[vt], 0, 0, 0);
      }
    }
  }
  const int b = bh >> 4, h = bh & 15;
  float inv = 1.f / l_i;
  u16* orow = O + ((size_t)(b * T_ + qg)) * 2048 + h * 128 + 4 * half;
#pragma unroll
  for (int vt = 0; vt < 4; vt++)
#pragma unroll
    for (int qd = 0; qd < 4; qd++) {
      uint2 pk;
      pk.x = pk2(oacc[vt][qd * 4 + 0] * inv, oacc[vt][qd * 4 + 1] * inv);
      pk.y = pk2(oacc[vt][qd * 4 + 2] * inv, oacc[vt][qd * 4 + 3] * inv);
      *(uint2*)(orow + vt * 32 + qd * 8) = pk;
    }
}

extern "C" void kernel_launch(void* const* d_in, const int* in_sizes, int n_in,
                              void* d_out, int out_size, void* d_ws, size_t ws_size,
                              hipStream_t stream) {
  const float* x    = (const float*)d_in[0];
  const float* fcos = (const float*)d_in[1];
  const float* fsin = (const float*)d_in[2];
  const float* wqd  = (const float*)d_in[3];
  const float* qnw  = (const float*)d_in[4];
  const float* wqun = (const float*)d_in[5];
  const float* wqur = (const float*)d_in[6];
  const float* wkvd = (const float*)d_in[7];
  const float* kvnw = (const float*)d_in[8];
  const float* wkvu = (const float*)d_in[9];
  const float* qhnw = (const float*)d_in[10];
  const float* khnw = (const float*)d_in[11];
  const float* wwo  = (const float*)d_in[12];
  float* out = (float*)d_out;
  char* ws = (char*)d_ws;

  size_t off = 0;
  auto alloc = [&](size_t elems) -> u16* {
    u16* p = (u16*)(ws + off);
    off += ((elems * 2 + 255) & ~(size_t)255);
    return p;
  };
  u16* x16   = alloc(4096ull * 2048);
  u16* bqkvd = alloc(2176ull * 2048);  // fused q_down(1536) + kv_down(640)
  u16* bqu   = alloc(3072ull * 1536);  // merged q_up
  u16* bkvu  = alloc(4096ull * 512);
  u16* bwo   = alloc(2048ull * 2048);
  u16* cqkv  = alloc(4096ull * 2176);  // fused down-proj output
  u16* cq    = alloc(4096ull * 1536);
  u16* qnr   = alloc(4096ull * 3072);
  u16* ckv   = alloc(4096ull * 512);
  u16* kvu   = alloc(4096ull * 4096);
  u16* qp    = alloc(32ull * 2048 * 192);
  u16* kp    = alloc(32ull * 2048 * 192);
  u16* vp    = alloc(32ull * 2048 * 128);
  u16* ao    = alloc(4096ull * 2048);
  if (ws_size < off) return;

  cast_f32_bf16<<<8192, 256, 0, stream>>>(x, x16, 4096 * 2048);
  castT<<<dim3(48, 64), 256, 0, stream>>>(wqd, bqkvd, 2048, 1536);
  castT<<<dim3(20, 64), 256, 0, stream>>>(wkvd, bqkvd + 1536ull * 2048, 2048, 576);
  castT<<<dim3(64, 48), 256, 0, stream>>>(wqun, bqu, 1536, 2048);
  castT<<<dim3(32, 48), 256, 0, stream>>>(wqur, bqu + 2048ull * 1536, 1536, 1024);
  castT<<<dim3(128, 16), 256, 0, stream>>>(wkvu, bkvu, 512, 4096);
  castT<<<dim3(64, 64), 256, 0, stream>>>(wwo, bwo, 2048, 2048);

  gemm_bt<<<dim3(17, 32), 256, 0, stream>>>(x16, bqkvd, cqkv, 4096, 2176, 2048, 0);
  rmsnorm_rows<<<4096, 256, 0, stream>>>(cqkv, cq, qnw, 1536, 2176, 1536);
  rmsnorm_rows<<<4096, 256, 0, stream>>>(cqkv + 1536, ckv, kvnw, 512, 2176, 512);
  gemm_bt<<<dim3(24, 32), 256, 0, stream>>>(cq, bqu, qnr, 4096, 3072, 1536, 0);
  gemm_bt<<<dim3(32, 32), 256, 0, stream>>>(ckv, bkvu, kvu, 4096, 4096, 512, 0);
  qpack<<<16384, 256, 0, stream>>>(qnr, qhnw, fcos, fsin, qp);
  kvpack<<<1024, 256, 0, stream>>>(kvu, cqkv + 1536, 2176, khnw, fcos, fsin, kp, vp);
  attn_kernel<<<dim3(16, 32), 256, 0, stream>>>(qp, kp, vp, ao);
  gemm_bt<<<dim3(16, 32), 256, 0, stream>>>(ao, bwo, out, 4096, 2048, 2048, 1);
}

// Round 5
// 509.493 us; speedup vs baseline: 1.4647x; 1.0107x over previous
//
#include <hip/hip_runtime.h>
#include <hip/hip_bf16.h>
#include <stdint.h>

typedef unsigned short u16;
typedef __bf16 bf16x8 __attribute__((ext_vector_type(8)));
typedef __attribute__((ext_vector_type(4))) float f32x4;
typedef __attribute__((ext_vector_type(16))) float f32x16;
typedef __attribute__((ext_vector_type(4))) unsigned short u16x4;
typedef __attribute__((ext_vector_type(4))) int i32x4;

#define T_ 2048

__device__ __forceinline__ u16 f2bf(float f) {
  __hip_bfloat16 h = __float2bfloat16(f);
  return __builtin_bit_cast(u16, h);
}
__device__ __forceinline__ float bf2f(u16 u) {
  __hip_bfloat16 h = __builtin_bit_cast(__hip_bfloat16, u);
  return __bfloat162float(h);
}
__device__ __forceinline__ unsigned pk2(float a, float b) {
  return (unsigned)f2bf(a) | ((unsigned)f2bf(b) << 16);
}

// ---------------- casts ----------------
__global__ __launch_bounds__(256) void cast_f32_bf16(const float* __restrict__ in,
                                                     u16* __restrict__ outp, int n) {
  int i = (blockIdx.x * 256 + threadIdx.x) * 4;
  if (i < n) {
    f32x4 v = *(const f32x4*)(in + i);
    u16x4 o;
    o.x = f2bf(v.x); o.y = f2bf(v.y); o.z = f2bf(v.z); o.w = f2bf(v.w);
    *(u16x4*)(outp + i) = o;
  }
}

// in fp32 [R][C] -> out bf16 [Cpad][R]; cols >= C write 0 (zero padding rows).
__global__ __launch_bounds__(256) void castT(const float* __restrict__ in,
                                             u16* __restrict__ outp, int R, int C) {
  __shared__ float tile[32][33];
  int tx = threadIdx.x & 31, ty = threadIdx.x >> 5;
  int r0 = blockIdx.y * 32, c0 = blockIdx.x * 32;
#pragma unroll
  for (int p = 0; p < 4; p++) {
    int rr = r0 + ty + p * 8;
    int cc = c0 + tx;
    tile[ty + p * 8][tx] = (cc < C) ? in[(size_t)rr * C + cc] : 0.f;
  }
  __syncthreads();
#pragma unroll
  for (int p = 0; p < 4; p++) {
    outp[(size_t)(c0 + ty + p * 8) * R + r0 + tx] = f2bf(tile[tx][ty + p * 8]);
  }
}

// ---------------- rmsnorm over rows ----------------
__global__ __launch_bounds__(256) void rmsnorm_rows(const u16* __restrict__ in,
                                                    u16* __restrict__ outp,
                                                    const float* __restrict__ w,
                                                    int D, int sin, int sout) {
  int r = blockIdx.x, tid = threadIdx.x;
  int wave = tid >> 6, lane = tid & 63;
  __shared__ float sred[4];
  float vals[6];
  int E = D >> 8;
  float ss = 0.f;
  for (int e = 0; e < E; e++) {
    float v = bf2f(in[(size_t)r * sin + e * 256 + tid]);
    vals[e] = v;
    ss += v * v;
  }
#pragma unroll
  for (int d = 1; d < 64; d <<= 1) ss += __shfl_xor(ss, d, 64);
  if (lane == 0) sred[wave] = ss;
  __syncthreads();
  ss = sred[0] + sred[1] + sred[2] + sred[3];
  float rr = rsqrtf(ss / (float)D + 1e-6f);
  for (int e = 0; e < E; e++)
    outp[(size_t)r * sout + e * 256 + tid] = f2bf(vals[e] * rr * w[e * 256 + tid]);
}

// ---------------- GEMM: C[M,N] = A[M,K] * Bt[N,K]^T  (bf16 in, fp32 acc) ----
// BK=64, register-prefetch double-buffer, XOR-swizzled LDS (chunk ^ (row&7)).
// K must be a multiple of 64.
__global__ __launch_bounds__(256) void gemm_bt(const u16* __restrict__ A,
                                               const u16* __restrict__ Bt,
                                               void* __restrict__ Cv,
                                               int M, int N, int K, int cf32) {
  __shared__ u16 As[128 * 64];
  __shared__ u16 Bs[128 * 64];
  const int tid = threadIdx.x;
  const int wave = tid >> 6, lane = tid & 63;
  const int m0 = blockIdx.y * 128, n0 = blockIdx.x * 128;
  const int wm = (wave >> 1) * 64, wn = (wave & 1) * 64;
  const int fr = lane & 15, fq = lane >> 4;
  f32x4 acc[4][4] = {};

  // staging: thread owns row tid>>1, 64B at col-chunk base (tid&1)*4
  const int srow = tid >> 1;
  const int scb = (tid & 1) * 4;
  const u16* apg = A + (size_t)(m0 + srow) * K + scb * 8;
  const u16* bpg = Bt + (size_t)(n0 + srow) * K + scb * 8;
  u16* awp[4];
  u16* bwp[4];
#pragma unroll
  for (int i = 0; i < 4; i++) {
    int sw = ((scb + i) ^ (srow & 7)) << 3;
    awp[i] = As + srow * 64 + sw;
    bwp[i] = Bs + srow * 64 + sw;
  }
  // fragment read pointers [ks][i]
  const u16* ard[2][4];
  const u16* brd[2][4];
#pragma unroll
  for (int ks = 0; ks < 2; ks++)
#pragma unroll
    for (int i = 0; i < 4; i++) {
      int ra = wm + 16 * i + fr;
      ard[ks][i] = As + ra * 64 + (((fq + ks * 4) ^ (ra & 7)) << 3);
      int rb = wn + 16 * i + fr;
      brd[ks][i] = Bs + rb * 64 + (((fq + ks * 4) ^ (rb & 7)) << 3);
    }

  i32x4 areg[4], breg[4];
#pragma unroll
  for (int i = 0; i < 4; i++) {
    areg[i] = *(const i32x4*)(apg + i * 8);
    breg[i] = *(const i32x4*)(bpg + i * 8);
  }

  for (int k0 = 0; k0 < K; k0 += 64) {
    if (k0) __syncthreads();
#pragma unroll
    for (int i = 0; i < 4; i++) {
      *(i32x4*)awp[i] = areg[i];
      *(i32x4*)bwp[i] = breg[i];
    }
    __syncthreads();
    if (k0 + 64 < K) {
#pragma unroll
      for (int i = 0; i < 4; i++) {
        areg[i] = *(const i32x4*)(apg + k0 + 64 + i * 8);
        breg[i] = *(const i32x4*)(bpg + k0 + 64 + i * 8);
      }
    }
#pragma unroll
    for (int ks = 0; ks < 2; ks++) {
      bf16x8 af[4], bf[4];
#pragma unroll
      for (int i = 0; i < 4; i++) {
        af[i] = *(const bf16x8*)ard[ks][i];
        bf[i] = *(const bf16x8*)brd[ks][i];
      }
#pragma unroll
      for (int i = 0; i < 4; i++)
#pragma unroll
        for (int j = 0; j < 4; j++)
          acc[i][j] = __builtin_amdgcn_mfma_f32_16x16x32_bf16(af[i], bf[j], acc[i][j], 0, 0, 0);
    }
  }
  if (cf32) {
    float* C = (float*)Cv;
#pragma unroll
    for (int i = 0; i < 4; i++)
#pragma unroll
      for (int j = 0; j < 4; j++)
#pragma unroll
        for (int r = 0; r < 4; r++)
          C[(size_t)(m0 + wm + 16 * i + fq * 4 + r) * N + n0 + wn + 16 * j + fr] = acc[i][j][r];
  } else {
    u16* C = (u16*)Cv;
#pragma unroll
    for (int i = 0; i < 4; i++)
#pragma unroll
      for (int j = 0; j < 4; j++)
#pragma unroll
        for (int r = 0; r < 4; r++)
          C[(size_t)(m0 + wm + 16 * i + fq * 4 + r) * N + n0 + wn + 16 * j + fr] = f2bf(acc[i][j][r]);
  }
}

// ---------------- q pack: head rmsnorm + rope + 1/sqrt(192) scale ----------
__global__ __launch_bounds__(256) void qpack(const u16* __restrict__ qnr,
                                             const float* __restrict__ qhw,
                                             const float* __restrict__ fcos,
                                             const float* __restrict__ fsin,
                                             u16* __restrict__ qp) {
  int gw = blockIdx.x * 4 + (threadIdx.x >> 6);
  int lane = threadIdx.x & 63;
  int r = gw >> 4, h = gw & 15;
  int b = r >> 11, t = r & 2047;
  const float sc = 0.07216878364870323f;  // 1/sqrt(192), folded into Q
  float v0 = bf2f(qnr[(size_t)r * 3072 + h * 128 + lane]);
  float v1 = bf2f(qnr[(size_t)r * 3072 + h * 128 + 64 + lane]);
  float ss = v0 * v0 + v1 * v1;
#pragma unroll
  for (int d = 1; d < 64; d <<= 1) ss += __shfl_xor(ss, d, 64);
  float rr = rsqrtf(ss * (1.f / 128.f) + 1e-6f) * sc;
  size_t ob = ((size_t)(b * 16 + h) * 2048 + t) * 192;
  qp[ob + lane] = f2bf(v0 * rr * qhw[lane]);
  qp[ob + 64 + lane] = f2bf(v1 * rr * qhw[64 + lane]);
  if (lane < 32) {
    float a = bf2f(qnr[(size_t)r * 3072 + 2048 + h * 64 + 2 * lane]);
    float bb = bf2f(qnr[(size_t)r * 3072 + 2048 + h * 64 + 2 * lane + 1]);
    float c = fcos[t * 32 + lane], s = fsin[t * 32 + lane];
    qp[ob + 128 + 2 * lane] = f2bf((a * c - bb * s) * sc);
    qp[ob + 129 + 2 * lane] = f2bf((a * s + bb * c) * sc);
  }
}

// ---------------- kv pack ----------------
__global__ __launch_bounds__(256) void kvpack(const u16* __restrict__ kvu,
                                              const u16* __restrict__ kvr,
                                              int ks,
                                              const float* __restrict__ khw,
                                              const float* __restrict__ fcos,
                                              const float* __restrict__ fsin,
                                              u16* __restrict__ kp,
                                              u16* __restrict__ vp) {
  int h = blockIdx.x & 15, tile = blockIdx.x >> 4;
  int r0 = tile * 64;
  int b = r0 >> 11;
  int tl = tile & 31;
  int tid = threadIdx.x, wave = tid >> 6, lane = tid & 63;
  __shared__ u16 vsl[128 * 66];
  int bh = b * 16 + h;
  for (int ii = 0; ii < 16; ii++) {
    int i = wave * 16 + ii;
    int r = r0 + i;
    int t = r & 2047;
    size_t kbase = (size_t)r * 4096 + h * 256;
    float v0 = bf2f(kvu[kbase + lane]);
    float v1 = bf2f(kvu[kbase + 64 + lane]);
    float ss = v0 * v0 + v1 * v1;
#pragma unroll
    for (int d = 1; d < 64; d <<= 1) ss += __shfl_xor(ss, d, 64);
    float rr = rsqrtf(ss * (1.f / 128.f) + 1e-6f);
    size_t ob = ((size_t)bh * 2048 + t) * 192;
    kp[ob + lane] = f2bf(v0 * rr * khw[lane]);
    kp[ob + 64 + lane] = f2bf(v1 * rr * khw[64 + lane]);
    vsl[lane * 66 + i] = kvu[kbase + 128 + lane];
    vsl[(lane + 64) * 66 + i] = kvu[kbase + 192 + lane];
    if (lane < 32) {
      float a = bf2f(kvr[(size_t)r * ks + 512 + 2 * lane]);
      float bb = bf2f(kvr[(size_t)r * ks + 512 + 2 * lane + 1]);
      float c = fcos[t * 32 + lane], s = fsin[t * 32 + lane];
      kp[ob + 128 + 2 * lane] = f2bf(a * c - bb * s);
      kp[ob + 129 + 2 * lane] = f2bf(a * s + bb * c);
    }
  }
  __syncthreads();
  u16* vb = vp + ((size_t)bh * 32 + tl) * 8192;  // [128 v][64 t] tile
  for (int u = 0; u < 32; u++) {
    int e = u * 256 + tid;
    vb[e] = vsl[(e >> 6) * 66 + (e & 63)];
  }
}

// ---------------- flash attention (causal), S^T formulation ----------------
// Causal pairing: block processes q-blocks {blockIdx.x, 15-blockIdx.x} ->
// uniform 34 K-tiles per block, grid 8x32 = 256 blocks (1/CU), no tail.
__global__ __launch_bounds__(256, 2) void attn_kernel(const u16* __restrict__ Q,
                                                      const u16* __restrict__ Kp,
                                                      const u16* __restrict__ Vt,
                                                      u16* __restrict__ O) {
  __shared__ u16 Ks[64 * 256];
  __shared__ u16 Vs[128 * 64];
  __shared__ u16 Ps[4][32 * 64];
  const int tid = threadIdx.x;
  const int wave = tid >> 6, lane = tid & 63;
  const int bh = blockIdx.y;
  const int l31 = lane & 31, half = lane >> 5, xr = lane & 7;
  const int b = bh >> 4, h = bh & 15;

  const char* kgb = (const char*)(Kp + (size_t)bh * T_ * 192);
  const char* vgb = (const char*)(Vt + (size_t)bh * 32 * 8192);
  u16* kw[6];
  u16* vw[4];
#pragma unroll
  for (int c = 0; c < 6; c++) {
    unsigned fo = c * 4096 + tid * 16;
    unsigned row = fo / 384u;
    unsigned chunk = (fo - row * 384) >> 4;
    kw[c] = Ks + row * 256 + ((chunk ^ (row & 7)) << 3);
  }
#pragma unroll
  for (int c = 0; c < 4; c++) {
    unsigned fo = c * 4096 + tid * 16;
    unsigned row = fo >> 7;
    unsigned chunk = (fo >> 4) & 7;
    vw[c] = Vs + row * 64 + ((chunk ^ (row & 7)) << 3);
  }
  const u16* krd0 = Ks + l31 * 256;
  const u16* krd1 = Ks + (32 + l31) * 256;
  const u16* vrd = Vs + l31 * 64;
  u16* pw = Ps[wave];
  const u16* prd = pw + l31 * 64;
  i32x4 kreg[6], vreg[4];

  for (int hidx = 0; hidx < 2; hidx++) {
    const int qb = hidx ? (15 - (int)blockIdx.x) : (int)blockIdx.x;
    const int qw0 = qb * 128 + wave * 32;
    const int qg = qw0 + l31;
    const int jmax = 2 * qb + 1;

    bf16x8 qf[12];
    {
      const u16* qbp = Q + ((size_t)bh * T_ + qg) * 192 + half * 8;
#pragma unroll
      for (int t = 0; t < 12; t++) qf[t] = *(const bf16x8*)(qbp + t * 16);
    }
    f32x16 oacc[4] = {};
    float m_i = -3.0e38f, l_i = 0.f;

#pragma unroll
    for (int c = 0; c < 6; c++) kreg[c] = *(const i32x4*)(kgb + c * 4096 + tid * 16);
#pragma unroll
    for (int c = 0; c < 4; c++) vreg[c] = *(const i32x4*)(vgb + c * 4096 + tid * 16);

    for (int j = 0; j <= jmax; j++) {
      if (j || hidx) __syncthreads();
#pragma unroll
      for (int c = 0; c < 6; c++) *(i32x4*)kw[c] = kreg[c];
#pragma unroll
      for (int c = 0; c < 4; c++) *(i32x4*)vw[c] = vreg[c];
      __syncthreads();
      if (j < jmax) {
        const char* kg = kgb + (size_t)(j + 1) * 24576;
        const char* vg = vgb + (size_t)(j + 1) * 16384;
#pragma unroll
        for (int c = 0; c < 6; c++) kreg[c] = *(const i32x4*)(kg + c * 4096 + tid * 16);
#pragma unroll
        for (int c = 0; c < 4; c++) vreg[c] = *(const i32x4*)(vg + c * 4096 + tid * 16);
      }
      if (j * 64 > qw0 + 31) continue;

      f32x16 sa[2] = {};
#pragma unroll
      for (int t = 0; t < 12; t++) {
        int sl = ((2 * t + half) ^ xr) << 3;
        bf16x8 a0 = *(const bf16x8*)(krd0 + sl);
        bf16x8 a1 = *(const bf16x8*)(krd1 + sl);
        sa[0] = __builtin_amdgcn_mfma_f32_32x32x16_bf16(a0, qf[t], sa[0], 0, 0, 0);
        sa[1] = __builtin_amdgcn_mfma_f32_32x32x16_bf16(a1, qf[t], sa[1], 0, 0, 0);
      }
      if (j * 64 + 63 > qw0) {
        int kb = j * 64 + 4 * half;
#pragma unroll
        for (int tt = 0; tt < 2; tt++)
#pragma unroll
          for (int r = 0; r < 16; r++) {
            int kk = kb + tt * 32 + (r & 3) + 8 * (r >> 2);
            if (kk > qg) sa[tt][r] = -3.0e38f;
          }
      }
      float mx = -3.0e38f;
#pragma unroll
      for (int r = 0; r < 16; r++) mx = fmaxf(mx, fmaxf(sa[0][r], sa[1][r]));
      mx = fmaxf(mx, __shfl_xor(mx, 32, 64));
      float mn = fmaxf(m_i, mx);
      float al = exp2f((m_i - mn) * 1.44269504f);
      float rs = 0.f;
#pragma unroll
      for (int tt = 0; tt < 2; tt++)
#pragma unroll
        for (int r = 0; r < 16; r++) {
          float p = exp2f((sa[tt][r] - mn) * 1.44269504f);
          sa[tt][r] = p;
          rs += p;
        }
      rs += __shfl_xor(rs, 32, 64);
      m_i = mn;
      l_i = l_i * al + rs;
#pragma unroll
      for (int vt = 0; vt < 4; vt++)
#pragma unroll
        for (int r = 0; r < 16; r++) oacc[vt][r] *= al;
#pragma unroll
      for (int tt = 0; tt < 2; tt++)
#pragma unroll
        for (int qd = 0; qd < 4; qd++) {
          uint2 pk;
          pk.x = pk2(sa[tt][qd * 4 + 0], sa[tt][qd * 4 + 1]);
          pk.y = pk2(sa[tt][qd * 4 + 2], sa[tt][qd * 4 + 3]);
          *(uint2*)(pw + l31 * 64 + (((4 * tt + qd) ^ (l31 & 7)) << 3) + half * 4) = pk;
        }
      __asm__ __volatile__("s_waitcnt lgkmcnt(0)" ::: "memory");
#pragma unroll
      for (int t = 0; t < 4; t++) {
        bf16x8 pf = *(const bf16x8*)(prd + (((2 * t + half) ^ (l31 & 7)) << 3));
#pragma unroll
        for (int vt = 0; vt < 4; vt++) {
          bf16x8 vf = *(const bf16x8*)(vrd + vt * 32 * 64 + (((2 * t + half) ^ xr) << 3));
          oacc[vt] = __builtin_amdgcn_mfma_f32_32x32x16_bf16(vf, pf, oacc[vt], 0, 0, 0);
        }
      }
    }
    float inv = 1.f / l_i;
    u16* orow = O + ((size_t)(b * T_ + qg)) * 2048 + h * 128 + 4 * half;
#pragma unroll
    for (int vt = 0; vt < 4; vt++)
#pragma unroll
      for (int qd = 0; qd < 4; qd++) {
        uint2 pk;
        pk.x = pk2(oacc[vt][qd * 4 + 0] * inv, oacc[vt][qd * 4 + 1] * inv);
        pk.y = pk2(oacc[vt][qd * 4 + 2] * inv, oacc[vt][qd * 4 + 3] * inv);
        *(uint2*)(orow + vt * 32 + qd * 8) = pk;
      }
  }
}

extern "C" void kernel_launch(void* const* d_in, const int* in_sizes, int n_in,
                              void* d_out, int out_size, void* d_ws, size_t ws_size,
                              hipStream_t stream) {
  const float* x    = (const float*)d_in[0];
  const float* fcos = (const float*)d_in[1];
  const float* fsin = (const float*)d_in[2];
  const float* wqd  = (const float*)d_in[3];
  const float* qnw  = (const float*)d_in[4];
  const float* wqun = (const float*)d_in[5];
  const float* wqur = (const float*)d_in[6];
  const float* wkvd = (const float*)d_in[7];
  const float* kvnw = (const float*)d_in[8];
  const float* wkvu = (const float*)d_in[9];
  const float* qhnw = (const float*)d_in[10];
  const float* khnw = (const float*)d_in[11];
  const float* wwo  = (const float*)d_in[12];
  float* out = (float*)d_out;
  char* ws = (char*)d_ws;

  size_t off = 0;
  auto alloc = [&](size_t elems) -> u16* {
    u16* p = (u16*)(ws + off);
    off += ((elems * 2 + 255) & ~(size_t)255);
    return p;
  };
  u16* x16   = alloc(4096ull * 2048);
  u16* bqkvd = alloc(2176ull * 2048);  // fused q_down(1536) + kv_down(640)
  u16* bqu   = alloc(3072ull * 1536);  // merged q_up
  u16* bkvu  = alloc(4096ull * 512);
  u16* bwo   = alloc(2048ull * 2048);
  u16* cqkv  = alloc(4096ull * 2176);  // fused down-proj output
  u16* cq    = alloc(4096ull * 1536);
  u16* qnr   = alloc(4096ull * 3072);
  u16* ckv   = alloc(4096ull * 512);
  u16* kvu   = alloc(4096ull * 4096);
  u16* qp    = alloc(32ull * 2048 * 192);
  u16* kp    = alloc(32ull * 2048 * 192);
  u16* vp    = alloc(32ull * 2048 * 128);
  u16* ao    = alloc(4096ull * 2048);
  if (ws_size < off) return;

  cast_f32_bf16<<<8192, 256, 0, stream>>>(x, x16, 4096 * 2048);
  castT<<<dim3(48, 64), 256, 0, stream>>>(wqd, bqkvd, 2048, 1536);
  castT<<<dim3(20, 64), 256, 0, stream>>>(wkvd, bqkvd + 1536ull * 2048, 2048, 576);
  castT<<<dim3(64, 48), 256, 0, stream>>>(wqun, bqu, 1536, 2048);
  castT<<<dim3(32, 48), 256, 0, stream>>>(wqur, bqu + 2048ull * 1536, 1536, 1024);
  castT<<<dim3(128, 16), 256, 0, stream>>>(wkvu, bkvu, 512, 4096);
  castT<<<dim3(64, 64), 256, 0, stream>>>(wwo, bwo, 2048, 2048);

  gemm_bt<<<dim3(17, 32), 256, 0, stream>>>(x16, bqkvd, cqkv, 4096, 2176, 2048, 0);
  rmsnorm_rows<<<4096, 256, 0, stream>>>(cqkv, cq, qnw, 1536, 2176, 1536);
  rmsnorm_rows<<<4096, 256, 0, stream>>>(cqkv + 1536, ckv, kvnw, 512, 2176, 512);
  gemm_bt<<<dim3(24, 32), 256, 0, stream>>>(cq, bqu, qnr, 4096, 3072, 1536, 0);
  gemm_bt<<<dim3(32, 32), 256, 0, stream>>>(ckv, bkvu, kvu, 4096, 4096, 512, 0);
  qpack<<<16384, 256, 0, stream>>>(qnr, qhnw, fcos, fsin, qp);
  kvpack<<<1024, 256, 0, stream>>>(kvu, cqkv + 1536, 2176, khnw, fcos, fsin, kp, vp);
  attn_kernel<<<dim3(8, 32), 256, 0, stream>>>(qp, kp, vp, ao);
  gemm_bt<<<dim3(16, 32), 256, 0, stream>>>(ao, bwo, out, 4096, 2048, 2048, 1);
}